// Round 7
// baseline (532.620 us; speedup 1.0000x reference)
//
#include <hip/hip_runtime.h>
#include <hip/hip_bf16.h>
#include <stdint.h>
#include <stddef.h>

typedef __bf16 bf16_t;
typedef __bf16 bf16x8 __attribute__((ext_vector_type(8)));
typedef float floatx4 __attribute__((ext_vector_type(4)));

#define DIM 512
#define SEQ 4096
#define BATCH 8

static __device__ __forceinline__ floatx4 mfma_bf16(bf16x8 a, bf16x8 b, floatx4 c) {
  return __builtin_amdgcn_mfma_f32_16x16x32_bf16(a, b, c, 0, 0, 0);
}

typedef __attribute__((address_space(1))) const void* gas_ptr;
typedef __attribute__((address_space(3))) void* las_ptr;
static __device__ __forceinline__ void gll16(const void* g, void* l) {
  __builtin_amdgcn_global_load_lds((gas_ptr)g, (las_ptr)l, 16, 0, 0);
}

// ---------------- K0: fp32 -> bf16 converter (w_qkv and x) ----------------
__global__ __launch_bounds__(256) void k_cvt(const float* __restrict__ w, bf16_t* __restrict__ wb) {
  int i = (blockIdx.x * 256 + threadIdx.x) * 8;
  float4 a = *(const float4*)&w[i];
  float4 b = *(const float4*)&w[i + 4];
  bf16x8 o;
  o[0] = (bf16_t)a.x; o[1] = (bf16_t)a.y; o[2] = (bf16_t)a.z; o[3] = (bf16_t)a.w;
  o[4] = (bf16_t)b.x; o[5] = (bf16_t)b.y; o[6] = (bf16_t)b.z; o[7] = (bf16_t)b.w;
  *(bf16x8*)&wb[i] = o;
}

// ---------------- K1: qkv GEMM, 256x256 tile, 8 waves, BK=64 ----------------
// LDS[row][u16] = G[row][u16 ^ (row&7)]; read back with same XOR. 0-conflict (r5 verified).
// launch_bounds(512,4): 4 waves/EU -> 2 blocks/CU (r6 lesson: (512,2) gave only 1).
__global__ __launch_bounds__(512, 4) void k_qkv(const bf16_t* __restrict__ Xb,
                                                const bf16_t* __restrict__ Wb,
                                                bf16_t* __restrict__ qs,
                                                bf16_t* __restrict__ ek,
                                                bf16_t* __restrict__ vb,
                                                float* __restrict__ S) {
  __shared__ __align__(16) bf16_t As[256 * 64];  // 32 KB
  __shared__ __align__(16) bf16_t Bs[256 * 64];  // 32 KB
  const int tid = threadIdx.x;
  const int lane = tid & 63;
  const int w = tid >> 6;              // 0..7
  const int wr = w >> 2, wc = w & 3;   // wave tile 128 x 64
  const int l15 = lane & 15, l4 = lane >> 4;
  const int m0 = blockIdx.x * 256;
  const int n0 = blockIdx.y * 256;

  const int srow = tid >> 3;
  const int sunit = (tid & 7) ^ (srow & 7);
  const bf16_t* gA = Xb + (size_t)(m0 + srow) * DIM + (sunit << 3);
  const bf16_t* gB = Wb + (size_t)(n0 + srow) * DIM + (sunit << 3);
  bf16_t* lA = As + tid * 8;
  bf16_t* lB = Bs + tid * 8;

  floatx4 acc[8][4];
#pragma unroll
  for (int i = 0; i < 8; ++i)
#pragma unroll
    for (int j = 0; j < 4; ++j) acc[i][j] = (floatx4){0.f, 0.f, 0.f, 0.f};

  for (int kt = 0; kt < DIM; kt += 64) {
#pragma unroll
    for (int i = 0; i < 4; ++i) {
      gll16(gA + (size_t)i * 64 * DIM, lA + i * 64 * 64);
      gll16(gB + (size_t)i * 64 * DIM, lB + i * 64 * 64);
    }
    gA += 64; gB += 64;
    __syncthreads();
#pragma unroll
    for (int kk = 0; kk < 2; ++kk) {
      bf16x8 af[8], bfr[4];
#pragma unroll
      for (int f = 0; f < 8; ++f) {
        int ar = wr * 128 + f * 16 + l15;
        int ua = (kk * 4 + l4) ^ (ar & 7);
        af[f] = *(const bf16x8*)(As + ar * 64 + ua * 8);
      }
#pragma unroll
      for (int f = 0; f < 4; ++f) {
        int br = wc * 64 + f * 16 + l15;
        int ub = (kk * 4 + l4) ^ (br & 7);
        bfr[f] = *(const bf16x8*)(Bs + br * 64 + ub * 8);
      }
#pragma unroll
      for (int i = 0; i < 8; ++i)
#pragma unroll
        for (int j = 0; j < 4; ++j)
          acc[i][j] = mfma_bf16(af[i], bfr[j], acc[i][j]);
    }
    __syncthreads();
  }

  const int colbase = n0 + wc * 64;
  if (n0 < 512) {
#pragma unroll
    for (int fm = 0; fm < 8; ++fm) {
#pragma unroll
      for (int r = 0; r < 4; ++r) {
        float v0 = acc[fm][0][r], v1 = acc[fm][1][r], v2 = acc[fm][2][r], v3 = acc[fm][3][r];
        float mx = fmaxf(fmaxf(v0, v1), fmaxf(v2, v3));
        mx = fmaxf(mx, __shfl_xor(mx, 1));
        mx = fmaxf(mx, __shfl_xor(mx, 2));
        mx = fmaxf(mx, __shfl_xor(mx, 4));
        mx = fmaxf(mx, __shfl_xor(mx, 8));
        float e0 = __expf(v0 - mx), e1 = __expf(v1 - mx), e2 = __expf(v2 - mx), e3 = __expf(v3 - mx);
        float s = e0 + e1 + e2 + e3;
        s += __shfl_xor(s, 1); s += __shfl_xor(s, 2); s += __shfl_xor(s, 4); s += __shfl_xor(s, 8);
        float inv = 0.125f / s;
        int m = m0 + wr * 128 + fm * 16 + l4 * 4 + r;
        bf16_t* rowp = qs + (size_t)m * DIM + colbase;
        rowp[l15]      = (bf16_t)(e0 * inv);
        rowp[16 + l15] = (bf16_t)(e1 * inv);
        rowp[32 + l15] = (bf16_t)(e2 * inv);
        rowp[48 + l15] = (bf16_t)(e3 * inv);
      }
    }
  } else if (n0 < 1024) {
    const int cb = colbase - 512;
    float c0 = 0.f, c1 = 0.f, c2 = 0.f, c3 = 0.f;
#pragma unroll
    for (int fm = 0; fm < 8; ++fm) {
#pragma unroll
      for (int r = 0; r < 4; ++r) {
        int m = m0 + wr * 128 + fm * 16 + l4 * 4 + r;
        bf16_t* rowp = ek + (size_t)m * DIM + cb;
        float e0 = __expf(acc[fm][0][r]);
        float e1 = __expf(acc[fm][1][r]);
        float e2 = __expf(acc[fm][2][r]);
        float e3 = __expf(acc[fm][3][r]);
        rowp[l15]      = (bf16_t)e0;
        rowp[16 + l15] = (bf16_t)e1;
        rowp[32 + l15] = (bf16_t)e2;
        rowp[48 + l15] = (bf16_t)e3;
        c0 += e0; c1 += e1; c2 += e2; c3 += e3;
      }
    }
    c0 += __shfl_xor(c0, 16); c0 += __shfl_xor(c0, 32);
    c1 += __shfl_xor(c1, 16); c1 += __shfl_xor(c1, 32);
    c2 += __shfl_xor(c2, 16); c2 += __shfl_xor(c2, 32);
    c3 += __shfl_xor(c3, 16); c3 += __shfl_xor(c3, 32);
    if (lane < 16) {
      int b = m0 >> 12;
      atomicAdd(&S[b * 512 + cb + lane],      c0);
      atomicAdd(&S[b * 512 + cb + 16 + lane], c1);
      atomicAdd(&S[b * 512 + cb + 32 + lane], c2);
      atomicAdd(&S[b * 512 + cb + 48 + lane], c3);
    }
  } else {
    const int cb = colbase - 1024;
#pragma unroll
    for (int fm = 0; fm < 8; ++fm) {
#pragma unroll
      for (int r = 0; r < 4; ++r) {
        int m = m0 + wr * 128 + fm * 16 + l4 * 4 + r;
        bf16_t* rowp = vb + (size_t)m * DIM + cb;
        rowp[l15]      = (bf16_t)acc[fm][0][r];
        rowp[16 + l15] = (bf16_t)acc[fm][1][r];
        rowp[32 + l15] = (bf16_t)acc[fm][2][r];
        rowp[48 + l15] = (bf16_t)acc[fm][3][r];
      }
    }
  }
}

// ---------------- K2: ctxpart[b,h,chunk] = ek_chunk^T @ v_chunk (64x64) ----------------
#define TP 136
__global__ __launch_bounds__(256) void k_ctx(const bf16_t* __restrict__ ek,
                                             const bf16_t* __restrict__ vb,
                                             float* __restrict__ ctxpart) {
  __shared__ __align__(16) bf16_t ekT[64 * TP];
  __shared__ __align__(16) bf16_t vT[64 * TP];
  __shared__ float red[4096];
  const int tid = threadIdx.x;
  const int lane = tid & 63, wid = tid >> 6;
  const int l15 = lane & 15, l4 = lane >> 4;
  const int bh = blockIdx.x, chunk = blockIdx.y;
  const int b = bh >> 3, h = bh & 7;
  const int base = b * SEQ + chunk * 512;

  floatx4 acc[4][4];
#pragma unroll
  for (int i = 0; i < 4; ++i)
#pragma unroll
    for (int j = 0; j < 4; ++j) acc[i][j] = (floatx4){0.f, 0.f, 0.f, 0.f};

  for (int nt = 0; nt < 4; ++nt) {
    const int n0 = base + nt * 128;
#pragma unroll
    for (int i = 0; i < 4; ++i) {
      int q = tid + i * 256;
      int n = q & 127;
      int c8 = (q >> 7) << 3;
      bf16x8 vk = *(const bf16x8*)&ek[(size_t)(n0 + n) * DIM + h * 64 + c8];
      bf16x8 vv = *(const bf16x8*)&vb[(size_t)(n0 + n) * DIM + h * 64 + c8];
#pragma unroll
      for (int j = 0; j < 8; ++j) {
        ekT[(c8 + j) * TP + n] = vk[j];
        vT [(c8 + j) * TP + n] = vv[j];
      }
    }
    __syncthreads();
    const int nb = wid * 32;
    bf16x8 af[4], bfr[4];
#pragma unroll
    for (int f = 0; f < 4; ++f) {
      af[f]  = *(const bf16x8*)&ekT[(f * 16 + l15) * TP + nb + l4 * 8];
      bfr[f] = *(const bf16x8*)&vT [(f * 16 + l15) * TP + nb + l4 * 8];
    }
#pragma unroll
    for (int i = 0; i < 4; ++i)
#pragma unroll
      for (int j = 0; j < 4; ++j)
        acc[i][j] = mfma_bf16(af[i], bfr[j], acc[i][j]);
    __syncthreads();
  }

  for (int w = 0; w < 4; ++w) {
    if (wid == w) {
#pragma unroll
      for (int fm = 0; fm < 4; ++fm)
#pragma unroll
        for (int fn = 0; fn < 4; ++fn)
#pragma unroll
          for (int r = 0; r < 4; ++r) {
            int d = fm * 16 + l4 * 4 + r;
            int e = fn * 16 + l15;
            if (w == 0) red[d * 64 + e] = acc[fm][fn][r];
            else        red[d * 64 + e] += acc[fm][fn][r];
          }
    }
    __syncthreads();
  }
  float* dst = ctxpart + ((size_t)bh * 8 + chunk) * 4096;
#pragma unroll
  for (int i = 0; i < 4; ++i) {
    int q = tid + i * 256;
    *(float4*)&dst[q * 4] = *(const float4*)&red[q * 4];
  }
}

// ---------------- K3: reduce partials, /S, then Mt[b][dcol][h*64+d] ----------------
__global__ __launch_bounds__(256) void k_mt(const float* __restrict__ ctxpart,
                                            const float* __restrict__ S,
                                            const float* __restrict__ w_out,
                                            bf16_t* __restrict__ Mt) {
  __shared__ float cs[4096];
  const int tid = threadIdx.x;
  const int bh = blockIdx.x;
  const int b = bh >> 3, h = bh & 7;
#pragma unroll
  for (int i = 0; i < 16; ++i) {
    int idx = tid + i * 256;
    float s = 0.f;
#pragma unroll
    for (int p = 0; p < 8; ++p) s += ctxpart[((size_t)bh * 8 + p) * 4096 + idx];
    cs[idx] = s / S[b * 512 + h * 64 + (idx >> 6)];
  }
  __syncthreads();
  for (int half = 0; half < 2; ++half) {
    const int dcol = half * 256 + tid;
    float a[64];
#pragma unroll
    for (int d = 0; d < 64; ++d) a[d] = 0.f;
    for (int e = 0; e < 64; ++e) {
      float we = w_out[(size_t)dcol * 512 + h * 64 + e];
#pragma unroll
      for (int d = 0; d < 64; ++d) a[d] += cs[d * 64 + e] * we;
    }
    bf16_t* dst = Mt + ((size_t)b * 512 + dcol) * 512 + h * 64;
#pragma unroll
    for (int g = 0; g < 8; ++g) {
      bf16x8 o;
#pragma unroll
      for (int j = 0; j < 8; ++j) o[j] = (bf16_t)a[g * 8 + j];
      *(bf16x8*)&dst[g * 8] = o;
    }
  }
}

// ---------------- K4: out = LN(qs[b] @ Mt[b]) fused. Tile 128 x 512 (full row), BK=32 ----------------
// LDS slot-swizzle (4 units/row): slot(r,u) = 4r + (u ^ (r&3) ^ ((r>>2)&3)); 2-way max (free).
__global__ __launch_bounds__(512, 4) void k_out(const bf16_t* __restrict__ qs,
                                                const bf16_t* __restrict__ Mt,
                                                const float* __restrict__ gamma,
                                                float* __restrict__ out) {
  __shared__ __align__(16) bf16_t As[128 * 32];   //  8 KB
  __shared__ __align__(16) bf16_t Bs[512 * 32];   // 32 KB
  __shared__ float redS[128 * 4];                 //  2 KB
  __shared__ float redQ[128 * 4];                 //  2 KB
  const int tid = threadIdx.x;
  const int lane = tid & 63;
  const int w = tid >> 6;
  const int wr = w >> 2, wc = w & 3;   // wave tile: 64 rows x 128 cols
  const int l15 = lane & 15, l4 = lane >> 4;
  const int m0 = blockIdx.x * 128;
  const bf16_t* Bp = Mt + (size_t)(blockIdx.x >> 5) * 512 * 512;

  // A staging: 512 slots, 1/thread. slot s=tid: r=s>>2, want unit u = (s&3)^(r&3)^((r>>2)&3)
  {
  }
  const int ra = tid >> 2;
  const int ua = (tid & 3) ^ (ra & 3) ^ ((ra >> 2) & 3);
  const bf16_t* gA = qs + (size_t)(m0 + ra) * 512 + (ua << 3);
  bf16_t* lA = As + tid * 8;
  // B staging: 2048 slots, 4/thread: s = tid + i*512, r = (tid>>2) + i*128
  const bf16_t* gBt[4];
  bf16_t* lBt[4];
#pragma unroll
  for (int i = 0; i < 4; ++i) {
    int rb = (tid >> 2) + i * 128;
    int ub = (tid & 3) ^ (rb & 3) ^ ((rb >> 2) & 3);
    gBt[i] = Bp + (size_t)rb * 512 + (ub << 3);
    lBt[i] = Bs + (tid + i * 512) * 8;
  }

  floatx4 acc[4][8];
#pragma unroll
  for (int i = 0; i < 4; ++i)
#pragma unroll
    for (int j = 0; j < 8; ++j) acc[i][j] = (floatx4){0.f, 0.f, 0.f, 0.f};

  for (int kt = 0; kt < 512; kt += 32) {
    gll16(gA + kt, lA);
#pragma unroll
    for (int i = 0; i < 4; ++i) gll16(gBt[i] + kt, lBt[i]);
    __syncthreads();
    bf16x8 af[4], bfr[8];
#pragma unroll
    for (int f = 0; f < 4; ++f) {
      int ar = wr * 64 + f * 16 + l15;
      int u = l4 ^ (ar & 3) ^ ((ar >> 2) & 3);
      af[f] = *(const bf16x8*)(As + ar * 32 + u * 8);
    }
#pragma unroll
    for (int f = 0; f < 8; ++f) {
      int br = wc * 128 + f * 16 + l15;
      int u = l4 ^ (br & 3) ^ ((br >> 2) & 3);
      bfr[f] = *(const bf16x8*)(Bs + br * 32 + u * 8);
    }
#pragma unroll
    for (int i = 0; i < 4; ++i)
#pragma unroll
      for (int j = 0; j < 8; ++j)
        acc[i][j] = mfma_bf16(af[i], bfr[j], acc[i][j]);
    __syncthreads();
  }

  // fused LayerNorm: rows m0 + wr*64 + fm*16 + l4*4 + r; cols wc*128 + fn*16 + l15
#pragma unroll
  for (int fm = 0; fm < 4; ++fm) {
#pragma unroll
    for (int r = 0; r < 4; ++r) {
      float s = 0.f, q = 0.f;
#pragma unroll
      for (int fn = 0; fn < 8; ++fn) {
        float v = acc[fm][fn][r];
        s += v; q += v * v;
      }
      s += __shfl_xor(s, 1); q += __shfl_xor(q, 1);
      s += __shfl_xor(s, 2); q += __shfl_xor(q, 2);
      s += __shfl_xor(s, 4); q += __shfl_xor(q, 4);
      s += __shfl_xor(s, 8); q += __shfl_xor(q, 8);
      if (l15 == 0) {
        int rl = wr * 64 + fm * 16 + l4 * 4 + r;
        redS[rl * 4 + wc] = s;
        redQ[rl * 4 + wc] = q;
      }
    }
  }
  __syncthreads();
  float gm[8];
#pragma unroll
  for (int fn = 0; fn < 8; ++fn) gm[fn] = gamma[wc * 128 + fn * 16 + l15];
#pragma unroll
  for (int fm = 0; fm < 4; ++fm) {
#pragma unroll
    for (int r = 0; r < 4; ++r) {
      int rl = wr * 64 + fm * 16 + l4 * 4 + r;
      float4 sv = *(const float4*)&redS[rl * 4];
      float4 qv = *(const float4*)&redQ[rl * 4];
      float S = sv.x + sv.y + sv.z + sv.w;
      float Q = qv.x + qv.y + qv.z + qv.w;
      float mean = S * (1.f / 512.f);
      float var = Q * (1.f / 512.f) - mean * mean;
      float rstd = rsqrtf(var + 1e-5f);
      float* rowp = out + (size_t)(m0 + rl) * 512 + wc * 128 + l15;
#pragma unroll
      for (int fn = 0; fn < 8; ++fn)
        rowp[fn * 16] = (acc[fm][fn][r] - mean) * rstd * gm[fn];
    }
  }
}

extern "C" void kernel_launch(void* const* d_in, const int* in_sizes, int n_in,
                              void* d_out, int out_size, void* d_ws, size_t ws_size,
                              hipStream_t stream) {
  const float* x     = (const float*)d_in[0];
  const float* w_qkv = (const float*)d_in[1];
  const float* w_out = (const float*)d_in[2];
  const float* gamma = (const float*)d_in[3];
  float* out = (float*)d_out;
  char* ws = (char*)d_ws;

  bf16_t* qs      = (bf16_t*)(ws);                       // 33,554,432
  bf16_t* ek      = (bf16_t*)(ws + 33554432);            // 33,554,432
  bf16_t* vb      = (bf16_t*)(ws + 67108864);            // 33,554,432
  bf16_t* wqkvb   = (bf16_t*)(ws + 100663296);           //  1,572,864
  float*  S       = (float*)(ws + 102236160);            //     16,384
  bf16_t* Xb      = (bf16_t*)(ws + 102252544);           // 33,554,432 (dead after k_qkv)
  float*  ctxpart = (float*)(ws + 103301120);            // alias Xb tail (written post-k_qkv)
  bf16_t* Mt      = (bf16_t*)(ws + 111689728);           // alias Xb tail

  hipMemsetAsync(S, 0, BATCH * 512 * sizeof(float), stream);

  k_cvt<<<384, 256, 0, stream>>>(w_qkv, wqkvb);
  k_cvt<<<8192, 256, 0, stream>>>(x, Xb);

  dim3 g1(128, 6);
  k_qkv<<<g1, 512, 0, stream>>>(Xb, wqkvb, qs, ek, vb, S);

  dim3 g2(64, 8);
  k_ctx<<<g2, 256, 0, stream>>>(ek, vb, ctxpart);

  k_mt<<<64, 256, 0, stream>>>(ctxpart, S, w_out, Mt);

  k_out<<<256, 512, 0, stream>>>(qs, Mt, gamma, out);
}

// Round 8
// 234.143 us; speedup vs baseline: 2.2748x; 2.2748x over previous
//
#include <hip/hip_runtime.h>
#include <hip/hip_bf16.h>
#include <stdint.h>
#include <stddef.h>

typedef __bf16 bf16_t;
typedef __bf16 bf16x8 __attribute__((ext_vector_type(8)));
typedef float floatx4 __attribute__((ext_vector_type(4)));

#define DIM 512
#define SEQ 4096
#define BATCH 8

static __device__ __forceinline__ floatx4 mfma_bf16(bf16x8 a, bf16x8 b, floatx4 c) {
  return __builtin_amdgcn_mfma_f32_16x16x32_bf16(a, b, c, 0, 0, 0);
}

typedef __attribute__((address_space(1))) const void* gas_ptr;
typedef __attribute__((address_space(3))) void* las_ptr;
static __device__ __forceinline__ void gll16(const void* g, void* l) {
  __builtin_amdgcn_global_load_lds((gas_ptr)g, (las_ptr)l, 16, 0, 0);
}

static __device__ __forceinline__ int swz(int row) { return (row & 3) ^ ((row >> 2) & 3); }

// ---------------- K0: fp32 -> bf16 converter (w_qkv and x) ----------------
__global__ __launch_bounds__(256) void k_cvt(const float* __restrict__ w, bf16_t* __restrict__ wb) {
  int i = (blockIdx.x * 256 + threadIdx.x) * 8;
  float4 a = *(const float4*)&w[i];
  float4 b = *(const float4*)&w[i + 4];
  bf16x8 o;
  o[0] = (bf16_t)a.x; o[1] = (bf16_t)a.y; o[2] = (bf16_t)a.z; o[3] = (bf16_t)a.w;
  o[4] = (bf16_t)b.x; o[5] = (bf16_t)b.y; o[6] = (bf16_t)b.z; o[7] = (bf16_t)b.w;
  *(bf16x8*)&wb[i] = o;
}

// ---------------- K1: qkv GEMM, 256x256 tile, 8 waves, BK=32, double-buffered 2-phase ----------------
// (512,2): acc[8][4]=128 acc regs needs the 256-reg budget (r7 lesson: (512,4) spills, 936MB scratch).
// LDS[row][u16] = G[row][u16 ^ swz(row)]; read with same XOR; 2-way max = free.
__global__ __launch_bounds__(512, 2) void k_qkv(const bf16_t* __restrict__ Xb,
                                                const bf16_t* __restrict__ Wb,
                                                bf16_t* __restrict__ qs,
                                                bf16_t* __restrict__ ek,
                                                bf16_t* __restrict__ vb,
                                                float* __restrict__ S) {
  __shared__ __align__(16) bf16_t As[2][256 * 32];  // 2 x 16 KB
  __shared__ __align__(16) bf16_t Bs[2][256 * 32];  // 2 x 16 KB
  const int tid = threadIdx.x;
  const int lane = tid & 63;
  const int w = tid >> 6;              // 0..7
  const int wr = w >> 2, wc = w & 3;   // wave tile 128 x 64
  const int l15 = lane & 15, l4 = lane >> 4;
  const int m0 = blockIdx.x * 256;
  const int n0 = blockIdx.y * 256;

  // staging: 1024 16B-slots per operand, 2 per thread
  const int s0 = tid, s1 = tid + 512;
  const int r0 = s0 >> 2, r1 = s1 >> 2;
  const int u0 = ((s0 & 3) ^ swz(r0)) << 3;
  const int u1 = ((s1 & 3) ^ swz(r1)) << 3;
  const bf16_t* gA0 = Xb + (size_t)(m0 + r0) * DIM + u0;
  const bf16_t* gA1 = Xb + (size_t)(m0 + r1) * DIM + u1;
  const bf16_t* gB0 = Wb + (size_t)(n0 + r0) * DIM + u0;
  const bf16_t* gB1 = Wb + (size_t)(n0 + r1) * DIM + u1;

  floatx4 acc[8][4];
#pragma unroll
  for (int i = 0; i < 8; ++i)
#pragma unroll
    for (int j = 0; j < 4; ++j) acc[i][j] = (floatx4){0.f, 0.f, 0.f, 0.f};

  // prologue: stage tile 0
  gll16(gA0, &As[0][s0 * 8]);
  gll16(gA1, &As[0][s1 * 8]);
  gll16(gB0, &Bs[0][s0 * 8]);
  gll16(gB1, &Bs[0][s1 * 8]);
  __syncthreads();

  for (int t = 0; t < 16; ++t) {
    const int cur = t & 1;
    if (t < 15) {  // stage t+1 into the other buffer (overlaps with compute below)
      const int kt = (t + 1) * 32;
      gll16(gA0 + kt, &As[cur ^ 1][s0 * 8]);
      gll16(gA1 + kt, &As[cur ^ 1][s1 * 8]);
      gll16(gB0 + kt, &Bs[cur ^ 1][s0 * 8]);
      gll16(gB1 + kt, &Bs[cur ^ 1][s1 * 8]);
    }
    bf16x8 af[8], bfr[4];
#pragma unroll
    for (int f = 0; f < 8; ++f) {
      int ar = wr * 128 + f * 16 + l15;
      int ua = l4 ^ swz(ar);
      af[f] = *(const bf16x8*)(&As[cur][ar * 32 + ua * 8]);
    }
#pragma unroll
    for (int f = 0; f < 4; ++f) {
      int br = wc * 64 + f * 16 + l15;
      int ub = l4 ^ swz(br);
      bfr[f] = *(const bf16x8*)(&Bs[cur][br * 32 + ub * 8]);
    }
#pragma unroll
    for (int i = 0; i < 8; ++i)
#pragma unroll
      for (int j = 0; j < 4; ++j)
        acc[i][j] = mfma_bf16(af[i], bfr[j], acc[i][j]);
    __syncthreads();  // drains vmcnt (tile t+1 landed) + protects buffer reuse
  }

  const int colbase = n0 + wc * 64;
  if (n0 < 512) {
#pragma unroll
    for (int fm = 0; fm < 8; ++fm) {
#pragma unroll
      for (int r = 0; r < 4; ++r) {
        float v0 = acc[fm][0][r], v1 = acc[fm][1][r], v2 = acc[fm][2][r], v3 = acc[fm][3][r];
        float mx = fmaxf(fmaxf(v0, v1), fmaxf(v2, v3));
        mx = fmaxf(mx, __shfl_xor(mx, 1));
        mx = fmaxf(mx, __shfl_xor(mx, 2));
        mx = fmaxf(mx, __shfl_xor(mx, 4));
        mx = fmaxf(mx, __shfl_xor(mx, 8));
        float e0 = __expf(v0 - mx), e1 = __expf(v1 - mx), e2 = __expf(v2 - mx), e3 = __expf(v3 - mx);
        float s = e0 + e1 + e2 + e3;
        s += __shfl_xor(s, 1); s += __shfl_xor(s, 2); s += __shfl_xor(s, 4); s += __shfl_xor(s, 8);
        float inv = 0.125f / s;
        int m = m0 + wr * 128 + fm * 16 + l4 * 4 + r;
        bf16_t* rowp = qs + (size_t)m * DIM + colbase;
        rowp[l15]      = (bf16_t)(e0 * inv);
        rowp[16 + l15] = (bf16_t)(e1 * inv);
        rowp[32 + l15] = (bf16_t)(e2 * inv);
        rowp[48 + l15] = (bf16_t)(e3 * inv);
      }
    }
  } else if (n0 < 1024) {
    const int cb = colbase - 512;
    float c0 = 0.f, c1 = 0.f, c2 = 0.f, c3 = 0.f;
#pragma unroll
    for (int fm = 0; fm < 8; ++fm) {
#pragma unroll
      for (int r = 0; r < 4; ++r) {
        int m = m0 + wr * 128 + fm * 16 + l4 * 4 + r;
        bf16_t* rowp = ek + (size_t)m * DIM + cb;
        float e0 = __expf(acc[fm][0][r]);
        float e1 = __expf(acc[fm][1][r]);
        float e2 = __expf(acc[fm][2][r]);
        float e3 = __expf(acc[fm][3][r]);
        rowp[l15]      = (bf16_t)e0;
        rowp[16 + l15] = (bf16_t)e1;
        rowp[32 + l15] = (bf16_t)e2;
        rowp[48 + l15] = (bf16_t)e3;
        c0 += e0; c1 += e1; c2 += e2; c3 += e3;
      }
    }
    c0 += __shfl_xor(c0, 16); c0 += __shfl_xor(c0, 32);
    c1 += __shfl_xor(c1, 16); c1 += __shfl_xor(c1, 32);
    c2 += __shfl_xor(c2, 16); c2 += __shfl_xor(c2, 32);
    c3 += __shfl_xor(c3, 16); c3 += __shfl_xor(c3, 32);
    if (lane < 16) {
      int b = m0 >> 12;
      atomicAdd(&S[b * 512 + cb + lane],      c0);
      atomicAdd(&S[b * 512 + cb + 16 + lane], c1);
      atomicAdd(&S[b * 512 + cb + 32 + lane], c2);
      atomicAdd(&S[b * 512 + cb + 48 + lane], c3);
    }
  } else {
    const int cb = colbase - 1024;
#pragma unroll
    for (int fm = 0; fm < 8; ++fm) {
#pragma unroll
      for (int r = 0; r < 4; ++r) {
        int m = m0 + wr * 128 + fm * 16 + l4 * 4 + r;
        bf16_t* rowp = vb + (size_t)m * DIM + cb;
        rowp[l15]      = (bf16_t)acc[fm][0][r];
        rowp[16 + l15] = (bf16_t)acc[fm][1][r];
        rowp[32 + l15] = (bf16_t)acc[fm][2][r];
        rowp[48 + l15] = (bf16_t)acc[fm][3][r];
      }
    }
  }
}

// ---------------- K2: ctxpart[b,h,chunk] = ek_chunk^T @ v_chunk (64x64) ----------------
#define TP 136
__global__ __launch_bounds__(256) void k_ctx(const bf16_t* __restrict__ ek,
                                             const bf16_t* __restrict__ vb,
                                             float* __restrict__ ctxpart) {
  __shared__ __align__(16) bf16_t ekT[64 * TP];
  __shared__ __align__(16) bf16_t vT[64 * TP];
  __shared__ float red[4096];
  const int tid = threadIdx.x;
  const int lane = tid & 63, wid = tid >> 6;
  const int l15 = lane & 15, l4 = lane >> 4;
  const int bh = blockIdx.x, chunk = blockIdx.y;
  const int b = bh >> 3, h = bh & 7;
  const int base = b * SEQ + chunk * 512;

  floatx4 acc[4][4];
#pragma unroll
  for (int i = 0; i < 4; ++i)
#pragma unroll
    for (int j = 0; j < 4; ++j) acc[i][j] = (floatx4){0.f, 0.f, 0.f, 0.f};

  for (int nt = 0; nt < 4; ++nt) {
    const int n0 = base + nt * 128;
#pragma unroll
    for (int i = 0; i < 4; ++i) {
      int q = tid + i * 256;
      int n = q & 127;
      int c8 = (q >> 7) << 3;
      bf16x8 vk = *(const bf16x8*)&ek[(size_t)(n0 + n) * DIM + h * 64 + c8];
      bf16x8 vv = *(const bf16x8*)&vb[(size_t)(n0 + n) * DIM + h * 64 + c8];
#pragma unroll
      for (int j = 0; j < 8; ++j) {
        ekT[(c8 + j) * TP + n] = vk[j];
        vT [(c8 + j) * TP + n] = vv[j];
      }
    }
    __syncthreads();
    const int nb = wid * 32;
    bf16x8 af[4], bfr[4];
#pragma unroll
    for (int f = 0; f < 4; ++f) {
      af[f]  = *(const bf16x8*)&ekT[(f * 16 + l15) * TP + nb + l4 * 8];
      bfr[f] = *(const bf16x8*)&vT [(f * 16 + l15) * TP + nb + l4 * 8];
    }
#pragma unroll
    for (int i = 0; i < 4; ++i)
#pragma unroll
      for (int j = 0; j < 4; ++j)
        acc[i][j] = mfma_bf16(af[i], bfr[j], acc[i][j]);
    __syncthreads();
  }

  for (int w = 0; w < 4; ++w) {
    if (wid == w) {
#pragma unroll
      for (int fm = 0; fm < 4; ++fm)
#pragma unroll
        for (int fn = 0; fn < 4; ++fn)
#pragma unroll
          for (int r = 0; r < 4; ++r) {
            int d = fm * 16 + l4 * 4 + r;
            int e = fn * 16 + l15;
            if (w == 0) red[d * 64 + e] = acc[fm][fn][r];
            else        red[d * 64 + e] += acc[fm][fn][r];
          }
    }
    __syncthreads();
  }
  float* dst = ctxpart + ((size_t)bh * 8 + chunk) * 4096;
#pragma unroll
  for (int i = 0; i < 4; ++i) {
    int q = tid + i * 256;
    *(float4*)&dst[q * 4] = *(const float4*)&red[q * 4];
  }
}

// ---------------- K3: reduce partials, /S, then Mt[b][dcol][h*64+d] ----------------
__global__ __launch_bounds__(256) void k_mt(const float* __restrict__ ctxpart,
                                            const float* __restrict__ S,
                                            const float* __restrict__ w_out,
                                            bf16_t* __restrict__ Mt) {
  __shared__ float cs[4096];
  const int tid = threadIdx.x;
  const int bh = blockIdx.x;
  const int b = bh >> 3, h = bh & 7;
#pragma unroll
  for (int i = 0; i < 16; ++i) {
    int idx = tid + i * 256;
    float s = 0.f;
#pragma unroll
    for (int p = 0; p < 8; ++p) s += ctxpart[((size_t)bh * 8 + p) * 4096 + idx];
    cs[idx] = s / S[b * 512 + h * 64 + (idx >> 6)];
  }
  __syncthreads();
  for (int half = 0; half < 2; ++half) {
    const int dcol = half * 256 + tid;
    float a[64];
#pragma unroll
    for (int d = 0; d < 64; ++d) a[d] = 0.f;
    for (int e = 0; e < 64; ++e) {
      float we = w_out[(size_t)dcol * 512 + h * 64 + e];
#pragma unroll
      for (int d = 0; d < 64; ++d) a[d] += cs[d * 64 + e] * we;
    }
    bf16_t* dst = Mt + ((size_t)b * 512 + dcol) * 512 + h * 64;
#pragma unroll
    for (int g = 0; g < 8; ++g) {
      bf16x8 o;
#pragma unroll
      for (int j = 0; j < 8; ++j) o[j] = (bf16_t)a[g * 8 + j];
      *(bf16x8*)&dst[g * 8] = o;
    }
  }
}

// ---------------- K4: out = LN(qs[b] @ Mt[b]) fused. 1024 thr, tile 128x512, wave 64x64, BK=32 ----------------
// acc[4][4]=64 regs fits the (1024,4) 128-reg budget (r7 lesson).
__global__ __launch_bounds__(1024, 4) void k_out(const bf16_t* __restrict__ qs,
                                                 const bf16_t* __restrict__ Mt,
                                                 const float* __restrict__ gamma,
                                                 float* __restrict__ out) {
  __shared__ __align__(16) bf16_t As[128 * 32];   //  8 KB
  __shared__ __align__(16) bf16_t Bs[512 * 32];   // 32 KB
  __shared__ float redS[128 * 8];                 //  4 KB
  __shared__ float redQ[128 * 8];                 //  4 KB
  const int tid = threadIdx.x;
  const int lane = tid & 63;
  const int w = tid >> 6;              // 0..15
  const int wr = w >> 3, wc = w & 7;   // wave tile 64 x 64 over (128, 512)
  const int l15 = lane & 15, l4 = lane >> 4;
  const int m0 = blockIdx.x * 128;
  const bf16_t* Bp = Mt + (size_t)(blockIdx.x >> 5) * 512 * 512;

  // A: 512 slots (threads 0..511, 1 each); B: 2048 slots (2 per thread)
  const int rA = tid >> 2;
  const int uA = ((tid & 3) ^ swz(rA)) << 3;
  const bf16_t* gA = qs + (size_t)(m0 + rA) * 512 + uA;
  const int sB0 = tid, sB1 = tid + 1024;
  const int rB0 = sB0 >> 2, rB1 = sB1 >> 2;
  const int uB0 = ((sB0 & 3) ^ swz(rB0)) << 3;
  const int uB1 = ((sB1 & 3) ^ swz(rB1)) << 3;
  const bf16_t* gB0 = Bp + (size_t)rB0 * 512 + uB0;
  const bf16_t* gB1 = Bp + (size_t)rB1 * 512 + uB1;

  floatx4 acc[4][4];
#pragma unroll
  for (int i = 0; i < 4; ++i)
#pragma unroll
    for (int j = 0; j < 4; ++j) acc[i][j] = (floatx4){0.f, 0.f, 0.f, 0.f};

  for (int kt = 0; kt < 512; kt += 32) {
    if (tid < 512) gll16(gA + kt, &As[tid * 8]);
    gll16(gB0 + kt, &Bs[sB0 * 8]);
    gll16(gB1 + kt, &Bs[sB1 * 8]);
    __syncthreads();
    bf16x8 af[4], bfr[4];
#pragma unroll
    for (int f = 0; f < 4; ++f) {
      int ar = wr * 64 + f * 16 + l15;
      int ua = l4 ^ swz(ar);
      af[f] = *(const bf16x8*)(&As[ar * 32 + ua * 8]);
      int br = wc * 64 + f * 16 + l15;
      int ub = l4 ^ swz(br);
      bfr[f] = *(const bf16x8*)(&Bs[br * 32 + ub * 8]);
    }
#pragma unroll
    for (int i = 0; i < 4; ++i)
#pragma unroll
      for (int j = 0; j < 4; ++j)
        acc[i][j] = mfma_bf16(af[i], bfr[j], acc[i][j]);
    __syncthreads();
  }

  // per-wave 64-col partials of each row
#pragma unroll
  for (int fm = 0; fm < 4; ++fm) {
#pragma unroll
    for (int r = 0; r < 4; ++r) {
      float s = 0.f, q = 0.f;
#pragma unroll
      for (int fn = 0; fn < 4; ++fn) {
        float v = acc[fm][fn][r];
        s += v; q += v * v;
      }
      s += __shfl_xor(s, 1); q += __shfl_xor(q, 1);
      s += __shfl_xor(s, 2); q += __shfl_xor(q, 2);
      s += __shfl_xor(s, 4); q += __shfl_xor(q, 4);
      s += __shfl_xor(s, 8); q += __shfl_xor(q, 8);
      if (l15 == 0) {
        int rl = wr * 64 + fm * 16 + l4 * 4 + r;
        redS[rl * 8 + wc] = s;
        redQ[rl * 8 + wc] = q;
      }
    }
  }
  __syncthreads();
  float gm[4];
#pragma unroll
  for (int fn = 0; fn < 4; ++fn) gm[fn] = gamma[wc * 64 + fn * 16 + l15];
#pragma unroll
  for (int fm = 0; fm < 4; ++fm) {
#pragma unroll
    for (int r = 0; r < 4; ++r) {
      int rl = wr * 64 + fm * 16 + l4 * 4 + r;
      float4 s0 = *(const float4*)&redS[rl * 8];
      float4 s1 = *(const float4*)&redS[rl * 8 + 4];
      float4 q0 = *(const float4*)&redQ[rl * 8];
      float4 q1 = *(const float4*)&redQ[rl * 8 + 4];
      float Sr = s0.x + s0.y + s0.z + s0.w + s1.x + s1.y + s1.z + s1.w;
      float Qr = q0.x + q0.y + q0.z + q0.w + q1.x + q1.y + q1.z + q1.w;
      float mean = Sr * (1.f / 512.f);
      float var = Qr * (1.f / 512.f) - mean * mean;
      float rstd = rsqrtf(var + 1e-5f);
      float* rowp = out + (size_t)(m0 + rl) * 512 + wc * 64 + l15;
#pragma unroll
      for (int fn = 0; fn < 4; ++fn)
        rowp[fn * 16] = (acc[fm][fn][r] - mean) * rstd * gm[fn];
    }
  }
}

extern "C" void kernel_launch(void* const* d_in, const int* in_sizes, int n_in,
                              void* d_out, int out_size, void* d_ws, size_t ws_size,
                              hipStream_t stream) {
  const float* x     = (const float*)d_in[0];
  const float* w_qkv = (const float*)d_in[1];
  const float* w_out = (const float*)d_in[2];
  const float* gamma = (const float*)d_in[3];
  float* out = (float*)d_out;
  char* ws = (char*)d_ws;

  bf16_t* qs      = (bf16_t*)(ws);                       // 33,554,432
  bf16_t* ek      = (bf16_t*)(ws + 33554432);            // 33,554,432
  bf16_t* vb      = (bf16_t*)(ws + 67108864);            // 33,554,432
  bf16_t* wqkvb   = (bf16_t*)(ws + 100663296);           //  1,572,864
  float*  S       = (float*)(ws + 102236160);            //     16,384
  bf16_t* Xb      = (bf16_t*)(ws + 102252544);           // 33,554,432 (dead after k_qkv)
  float*  ctxpart = (float*)(ws + 103301120);            // alias Xb tail (written post-k_qkv)
  bf16_t* Mt      = (bf16_t*)(ws + 111689728);           // alias Xb tail

  hipMemsetAsync(S, 0, BATCH * 512 * sizeof(float), stream);

  k_cvt<<<384, 256, 0, stream>>>(w_qkv, wqkvb);
  k_cvt<<<8192, 256, 0, stream>>>(x, Xb);

  dim3 g1(128, 6);
  k_qkv<<<g1, 512, 0, stream>>>(Xb, wqkvb, qs, ek, vb, S);

  dim3 g2(64, 8);
  k_ctx<<<g2, 256, 0, stream>>>(ek, vb, ctxpart);

  k_mt<<<64, 256, 0, stream>>>(ctxpart, S, w_out, Mt);

  k_out<<<256, 1024, 0, stream>>>(qs, Mt, gamma, out);
}

// Round 9
// 205.266 us; speedup vs baseline: 2.5948x; 1.1407x over previous
//
#include <hip/hip_runtime.h>
#include <hip/hip_bf16.h>
#include <stdint.h>
#include <stddef.h>

typedef __bf16 bf16_t;
typedef __bf16 bf16x8 __attribute__((ext_vector_type(8)));
typedef float floatx4 __attribute__((ext_vector_type(4)));

#define DIM 512
#define SEQ 4096
#define BATCH 8

static __device__ __forceinline__ floatx4 mfma_bf16(bf16x8 a, bf16x8 b, floatx4 c) {
  return __builtin_amdgcn_mfma_f32_16x16x32_bf16(a, b, c, 0, 0, 0);
}

typedef __attribute__((address_space(1))) const void* gas_ptr;
typedef __attribute__((address_space(3))) void* las_ptr;
static __device__ __forceinline__ void gll16(const void* g, void* l) {
  __builtin_amdgcn_global_load_lds((gas_ptr)g, (las_ptr)l, 16, 0, 0);
}

// ---------------- K0: fp32 -> bf16 converter (w_qkv and x) ----------------
__global__ __launch_bounds__(256) void k_cvt(const float* __restrict__ w, bf16_t* __restrict__ wb) {
  int i = (blockIdx.x * 256 + threadIdx.x) * 8;
  float4 a = *(const float4*)&w[i];
  float4 b = *(const float4*)&w[i + 4];
  bf16x8 o;
  o[0] = (bf16_t)a.x; o[1] = (bf16_t)a.y; o[2] = (bf16_t)a.z; o[3] = (bf16_t)a.w;
  o[4] = (bf16_t)b.x; o[5] = (bf16_t)b.y; o[6] = (bf16_t)b.z; o[7] = (bf16_t)b.w;
  *(bf16x8*)&wb[i] = o;
}

// ---------------- K1: qkv GEMM, 256x256 tile, 8 waves, BK=64, DOUBLE-BUFFERED ----------------
// 128B rows + u^(row&7): the only verified 0-conflict pattern (r5/r6; r8's 64B rows conflicted).
// Prefetch t+1 into alt buffer before computing t; 8 barriers total.
__global__ __launch_bounds__(512, 2) void k_qkv(const bf16_t* __restrict__ Xb,
                                                const bf16_t* __restrict__ Wb,
                                                bf16_t* __restrict__ qs,
                                                bf16_t* __restrict__ ek,
                                                bf16_t* __restrict__ vb,
                                                float* __restrict__ S) {
  __shared__ __align__(16) bf16_t As[2][256 * 64];  // 2 x 32 KB
  __shared__ __align__(16) bf16_t Bs[2][256 * 64];  // 2 x 32 KB
  const int tid = threadIdx.x;
  const int lane = tid & 63;
  const int w = tid >> 6;
  const int wr = w >> 2, wc = w & 3;   // wave tile 128 x 64
  const int l15 = lane & 15, l4 = lane >> 4;
  const int m0 = blockIdx.x * 256;
  const int n0 = blockIdx.y * 256;

  // staging: 2048 16B-slots per operand per buffer; 4 slots/thread
  int sr[4], su[4];
#pragma unroll
  for (int i = 0; i < 4; ++i) {
    int s = tid + i * 512;
    sr[i] = s >> 3;
    su[i] = ((s & 7) ^ (sr[i] & 7)) << 3;
  }

  floatx4 acc[8][4];
#pragma unroll
  for (int i = 0; i < 8; ++i)
#pragma unroll
    for (int j = 0; j < 4; ++j) acc[i][j] = (floatx4){0.f, 0.f, 0.f, 0.f};

  // prologue: stage tile 0 into buf 0
#pragma unroll
  for (int i = 0; i < 4; ++i) {
    int s = tid + i * 512;
    gll16(Xb + (size_t)(m0 + sr[i]) * DIM + su[i], &As[0][s * 8]);
    gll16(Wb + (size_t)(n0 + sr[i]) * DIM + su[i], &Bs[0][s * 8]);
  }
  __syncthreads();

  for (int t = 0; t < 8; ++t) {
    const int cur = t & 1;
    if (t < 7) {
      const int kt = (t + 1) * 64;
#pragma unroll
      for (int i = 0; i < 4; ++i) {
        int s = tid + i * 512;
        gll16(Xb + (size_t)(m0 + sr[i]) * DIM + kt + su[i], &As[cur ^ 1][s * 8]);
        gll16(Wb + (size_t)(n0 + sr[i]) * DIM + kt + su[i], &Bs[cur ^ 1][s * 8]);
      }
    }
#pragma unroll
    for (int kk = 0; kk < 2; ++kk) {
      bf16x8 af[8], bfr[4];
#pragma unroll
      for (int f = 0; f < 8; ++f) {
        int ar = wr * 128 + f * 16 + l15;
        int ua = (kk * 4 + l4) ^ (ar & 7);
        af[f] = *(const bf16x8*)(&As[cur][ar * 64 + ua * 8]);
      }
#pragma unroll
      for (int f = 0; f < 4; ++f) {
        int br = wc * 64 + f * 16 + l15;
        int ub = (kk * 4 + l4) ^ (br & 7);
        bfr[f] = *(const bf16x8*)(&Bs[cur][br * 64 + ub * 8]);
      }
#pragma unroll
      for (int i = 0; i < 8; ++i)
#pragma unroll
        for (int j = 0; j < 4; ++j)
          acc[i][j] = mfma_bf16(af[i], bfr[j], acc[i][j]);
    }
    __syncthreads();  // drains prefetch (vmcnt0) + protects buffer reuse
  }

  const int colbase = n0 + wc * 64;
  if (n0 < 512) {
#pragma unroll
    for (int fm = 0; fm < 8; ++fm) {
#pragma unroll
      for (int r = 0; r < 4; ++r) {
        float v0 = acc[fm][0][r], v1 = acc[fm][1][r], v2 = acc[fm][2][r], v3 = acc[fm][3][r];
        float mx = fmaxf(fmaxf(v0, v1), fmaxf(v2, v3));
        mx = fmaxf(mx, __shfl_xor(mx, 1));
        mx = fmaxf(mx, __shfl_xor(mx, 2));
        mx = fmaxf(mx, __shfl_xor(mx, 4));
        mx = fmaxf(mx, __shfl_xor(mx, 8));
        float e0 = __expf(v0 - mx), e1 = __expf(v1 - mx), e2 = __expf(v2 - mx), e3 = __expf(v3 - mx);
        float s = e0 + e1 + e2 + e3;
        s += __shfl_xor(s, 1); s += __shfl_xor(s, 2); s += __shfl_xor(s, 4); s += __shfl_xor(s, 8);
        float inv = 0.125f / s;
        int m = m0 + wr * 128 + fm * 16 + l4 * 4 + r;
        bf16_t* rowp = qs + (size_t)m * DIM + colbase;
        rowp[l15]      = (bf16_t)(e0 * inv);
        rowp[16 + l15] = (bf16_t)(e1 * inv);
        rowp[32 + l15] = (bf16_t)(e2 * inv);
        rowp[48 + l15] = (bf16_t)(e3 * inv);
      }
    }
  } else if (n0 < 1024) {
    const int cb = colbase - 512;
    float c0 = 0.f, c1 = 0.f, c2 = 0.f, c3 = 0.f;
#pragma unroll
    for (int fm = 0; fm < 8; ++fm) {
#pragma unroll
      for (int r = 0; r < 4; ++r) {
        int m = m0 + wr * 128 + fm * 16 + l4 * 4 + r;
        bf16_t* rowp = ek + (size_t)m * DIM + cb;
        float e0 = __expf(acc[fm][0][r]);
        float e1 = __expf(acc[fm][1][r]);
        float e2 = __expf(acc[fm][2][r]);
        float e3 = __expf(acc[fm][3][r]);
        rowp[l15]      = (bf16_t)e0;
        rowp[16 + l15] = (bf16_t)e1;
        rowp[32 + l15] = (bf16_t)e2;
        rowp[48 + l15] = (bf16_t)e3;
        c0 += e0; c1 += e1; c2 += e2; c3 += e3;
      }
    }
    c0 += __shfl_xor(c0, 16); c0 += __shfl_xor(c0, 32);
    c1 += __shfl_xor(c1, 16); c1 += __shfl_xor(c1, 32);
    c2 += __shfl_xor(c2, 16); c2 += __shfl_xor(c2, 32);
    c3 += __shfl_xor(c3, 16); c3 += __shfl_xor(c3, 32);
    if (lane < 16) {
      int b = m0 >> 12;
      atomicAdd(&S[b * 512 + cb + lane],      c0);
      atomicAdd(&S[b * 512 + cb + 16 + lane], c1);
      atomicAdd(&S[b * 512 + cb + 32 + lane], c2);
      atomicAdd(&S[b * 512 + cb + 48 + lane], c3);
    }
  } else {
    const int cb = colbase - 1024;
#pragma unroll
    for (int fm = 0; fm < 8; ++fm) {
#pragma unroll
      for (int r = 0; r < 4; ++r) {
        int m = m0 + wr * 128 + fm * 16 + l4 * 4 + r;
        bf16_t* rowp = vb + (size_t)m * DIM + cb;
        rowp[l15]      = (bf16_t)acc[fm][0][r];
        rowp[16 + l15] = (bf16_t)acc[fm][1][r];
        rowp[32 + l15] = (bf16_t)acc[fm][2][r];
        rowp[48 + l15] = (bf16_t)acc[fm][3][r];
      }
    }
  }
}

// ---------------- K2: ctxpart[b,h,chunk] = ek_chunk^T @ v_chunk (64x64) ----------------
#define TP 136
__global__ __launch_bounds__(256) void k_ctx(const bf16_t* __restrict__ ek,
                                             const bf16_t* __restrict__ vb,
                                             float* __restrict__ ctxpart) {
  __shared__ __align__(16) bf16_t ekT[64 * TP];
  __shared__ __align__(16) bf16_t vT[64 * TP];
  __shared__ float red[4096];
  const int tid = threadIdx.x;
  const int lane = tid & 63, wid = tid >> 6;
  const int l15 = lane & 15, l4 = lane >> 4;
  const int bh = blockIdx.x, chunk = blockIdx.y;
  const int b = bh >> 3, h = bh & 7;
  const int base = b * SEQ + chunk * 512;

  floatx4 acc[4][4];
#pragma unroll
  for (int i = 0; i < 4; ++i)
#pragma unroll
    for (int j = 0; j < 4; ++j) acc[i][j] = (floatx4){0.f, 0.f, 0.f, 0.f};

  for (int nt = 0; nt < 4; ++nt) {
    const int n0 = base + nt * 128;
#pragma unroll
    for (int i = 0; i < 4; ++i) {
      int q = tid + i * 256;
      int n = q & 127;
      int c8 = (q >> 7) << 3;
      bf16x8 vk = *(const bf16x8*)&ek[(size_t)(n0 + n) * DIM + h * 64 + c8];
      bf16x8 vv = *(const bf16x8*)&vb[(size_t)(n0 + n) * DIM + h * 64 + c8];
#pragma unroll
      for (int j = 0; j < 8; ++j) {
        ekT[(c8 + j) * TP + n] = vk[j];
        vT [(c8 + j) * TP + n] = vv[j];
      }
    }
    __syncthreads();
    const int nb = wid * 32;
    bf16x8 af[4], bfr[4];
#pragma unroll
    for (int f = 0; f < 4; ++f) {
      af[f]  = *(const bf16x8*)&ekT[(f * 16 + l15) * TP + nb + l4 * 8];
      bfr[f] = *(const bf16x8*)&vT [(f * 16 + l15) * TP + nb + l4 * 8];
    }
#pragma unroll
    for (int i = 0; i < 4; ++i)
#pragma unroll
      for (int j = 0; j < 4; ++j)
        acc[i][j] = mfma_bf16(af[i], bfr[j], acc[i][j]);
    __syncthreads();
  }

  for (int w = 0; w < 4; ++w) {
    if (wid == w) {
#pragma unroll
      for (int fm = 0; fm < 4; ++fm)
#pragma unroll
        for (int fn = 0; fn < 4; ++fn)
#pragma unroll
          for (int r = 0; r < 4; ++r) {
            int d = fm * 16 + l4 * 4 + r;
            int e = fn * 16 + l15;
            if (w == 0) red[d * 64 + e] = acc[fm][fn][r];
            else        red[d * 64 + e] += acc[fm][fn][r];
          }
    }
    __syncthreads();
  }
  float* dst = ctxpart + ((size_t)bh * 8 + chunk) * 4096;
#pragma unroll
  for (int i = 0; i < 4; ++i) {
    int q = tid + i * 256;
    *(float4*)&dst[q * 4] = *(const float4*)&red[q * 4];
  }
}

// ---------------- K3: reduce partials, /S, then Mt[b][dcol][h*64+d] ----------------
__global__ __launch_bounds__(256) void k_mt(const float* __restrict__ ctxpart,
                                            const float* __restrict__ S,
                                            const float* __restrict__ w_out,
                                            bf16_t* __restrict__ Mt) {
  __shared__ float cs[4096];
  const int tid = threadIdx.x;
  const int bh = blockIdx.x;
  const int b = bh >> 3, h = bh & 7;
#pragma unroll
  for (int i = 0; i < 16; ++i) {
    int idx = tid + i * 256;
    float s = 0.f;
#pragma unroll
    for (int p = 0; p < 8; ++p) s += ctxpart[((size_t)bh * 8 + p) * 4096 + idx];
    cs[idx] = s / S[b * 512 + h * 64 + (idx >> 6)];
  }
  __syncthreads();
  for (int half = 0; half < 2; ++half) {
    const int dcol = half * 256 + tid;
    float a[64];
#pragma unroll
    for (int d = 0; d < 64; ++d) a[d] = 0.f;
    for (int e = 0; e < 64; ++e) {
      float we = w_out[(size_t)dcol * 512 + h * 64 + e];
#pragma unroll
      for (int d = 0; d < 64; ++d) a[d] += cs[d * 64 + e] * we;
    }
    bf16_t* dst = Mt + ((size_t)b * 512 + dcol) * 512 + h * 64;
#pragma unroll
    for (int g = 0; g < 8; ++g) {
      bf16x8 o;
#pragma unroll
      for (int j = 0; j < 8; ++j) o[j] = (bf16_t)a[g * 8 + j];
      *(bf16x8*)&dst[g * 8] = o;
    }
  }
}

// ---------------- K4: out = LN(qs[b] @ Mt[b]) fused. 512 thr (512,2), tile 128x512, wave 64x128, BK=64 ----------------
// acc[4][8]=128 regs -> needs the 256-reg class, hence (512,2) (r7 lesson: never the 128-reg class).
__global__ __launch_bounds__(512, 2) void k_out(const bf16_t* __restrict__ qs,
                                                const bf16_t* __restrict__ Mt,
                                                const float* __restrict__ gamma,
                                                float* __restrict__ out) {
  __shared__ __align__(16) bf16_t As[128 * 64];   // 16 KB
  __shared__ __align__(16) bf16_t Bs[512 * 64];   // 64 KB
  __shared__ float redS[128 * 4];                 //  2 KB
  __shared__ float redQ[128 * 4];                 //  2 KB
  const int tid = threadIdx.x;
  const int lane = tid & 63;
  const int w = tid >> 6;
  const int wr = w >> 2, wc = w & 3;   // wave tile: 64 rows x 128 cols
  const int l15 = lane & 15, l4 = lane >> 4;
  const int m0 = blockIdx.x * 128;
  const bf16_t* Bp = Mt + (size_t)(blockIdx.x >> 5) * 512 * 512;

  floatx4 acc[4][8];
#pragma unroll
  for (int i = 0; i < 4; ++i)
#pragma unroll
    for (int j = 0; j < 8; ++j) acc[i][j] = (floatx4){0.f, 0.f, 0.f, 0.f};

  for (int kt = 0; kt < 512; kt += 64) {
    // A: 1024 slots, 2/thread; B: 4096 slots, 8/thread
#pragma unroll
    for (int i = 0; i < 2; ++i) {
      int s = tid + i * 512;
      int r = s >> 3;
      int u = ((s & 7) ^ (r & 7)) << 3;
      gll16(qs + (size_t)(m0 + r) * 512 + kt + u, &As[s * 8]);
    }
#pragma unroll
    for (int i = 0; i < 8; ++i) {
      int s = tid + i * 512;
      int r = s >> 3;
      int u = ((s & 7) ^ (r & 7)) << 3;
      gll16(Bp + (size_t)r * 512 + kt + u, &Bs[s * 8]);
    }
    __syncthreads();
#pragma unroll
    for (int kk = 0; kk < 2; ++kk) {
      bf16x8 af[4], bfr[8];
#pragma unroll
      for (int f = 0; f < 4; ++f) {
        int ar = wr * 64 + f * 16 + l15;
        int ua = (kk * 4 + l4) ^ (ar & 7);
        af[f] = *(const bf16x8*)(&As[ar * 64 + ua * 8]);
      }
#pragma unroll
      for (int f = 0; f < 8; ++f) {
        int br = wc * 128 + f * 16 + l15;
        int ub = (kk * 4 + l4) ^ (br & 7);
        bfr[f] = *(const bf16x8*)(&Bs[br * 64 + ub * 8]);
      }
#pragma unroll
      for (int i = 0; i < 4; ++i)
#pragma unroll
        for (int j = 0; j < 8; ++j)
          acc[i][j] = mfma_bf16(af[i], bfr[j], acc[i][j]);
    }
    __syncthreads();
  }

  // LN: per-wave partial over its 128-col band, cross-band via LDS
#pragma unroll
  for (int fm = 0; fm < 4; ++fm) {
#pragma unroll
    for (int r = 0; r < 4; ++r) {
      float s = 0.f, q = 0.f;
#pragma unroll
      for (int fn = 0; fn < 8; ++fn) {
        float v = acc[fm][fn][r];
        s += v; q += v * v;
      }
      s += __shfl_xor(s, 1); q += __shfl_xor(q, 1);
      s += __shfl_xor(s, 2); q += __shfl_xor(q, 2);
      s += __shfl_xor(s, 4); q += __shfl_xor(q, 4);
      s += __shfl_xor(s, 8); q += __shfl_xor(q, 8);
      if (l15 == 0) {
        int rl = wr * 64 + fm * 16 + l4 * 4 + r;
        redS[rl * 4 + wc] = s;
        redQ[rl * 4 + wc] = q;
      }
    }
  }
  __syncthreads();
  float gm[8];
#pragma unroll
  for (int fn = 0; fn < 8; ++fn) gm[fn] = gamma[wc * 128 + fn * 16 + l15];
#pragma unroll
  for (int fm = 0; fm < 4; ++fm) {
#pragma unroll
    for (int r = 0; r < 4; ++r) {
      int rl = wr * 64 + fm * 16 + l4 * 4 + r;
      float4 sv = *(const float4*)&redS[rl * 4];
      float4 qv = *(const float4*)&redQ[rl * 4];
      float Sr = sv.x + sv.y + sv.z + sv.w;
      float Qr = qv.x + qv.y + qv.z + qv.w;
      float mean = Sr * (1.f / 512.f);
      float var = Qr * (1.f / 512.f) - mean * mean;
      float rstd = rsqrtf(var + 1e-5f);
      float* rowp = out + (size_t)(m0 + rl) * 512 + wc * 128 + l15;
#pragma unroll
      for (int fn = 0; fn < 8; ++fn)
        rowp[fn * 16] = (acc[fm][fn][r] - mean) * rstd * gm[fn];
    }
  }
}

extern "C" void kernel_launch(void* const* d_in, const int* in_sizes, int n_in,
                              void* d_out, int out_size, void* d_ws, size_t ws_size,
                              hipStream_t stream) {
  const float* x     = (const float*)d_in[0];
  const float* w_qkv = (const float*)d_in[1];
  const float* w_out = (const float*)d_in[2];
  const float* gamma = (const float*)d_in[3];
  float* out = (float*)d_out;
  char* ws = (char*)d_ws;

  bf16_t* qs      = (bf16_t*)(ws);                       // 33,554,432
  bf16_t* ek      = (bf16_t*)(ws + 33554432);            // 33,554,432
  bf16_t* vb      = (bf16_t*)(ws + 67108864);            // 33,554,432
  bf16_t* wqkvb   = (bf16_t*)(ws + 100663296);           //  1,572,864
  float*  S       = (float*)(ws + 102236160);            //     16,384
  bf16_t* Xb      = (bf16_t*)(ws + 102252544);           // 33,554,432 (dead after k_qkv)
  float*  ctxpart = (float*)(ws + 103301120);            // alias Xb tail (written post-k_qkv)
  bf16_t* Mt      = (bf16_t*)(ws + 111689728);           // alias Xb tail

  hipMemsetAsync(S, 0, BATCH * 512 * sizeof(float), stream);

  k_cvt<<<384, 256, 0, stream>>>(w_qkv, wqkvb);
  k_cvt<<<8192, 256, 0, stream>>>(x, Xb);

  dim3 g1(128, 6);
  k_qkv<<<g1, 512, 0, stream>>>(Xb, wqkvb, qs, ek, vb, S);

  dim3 g2(64, 8);
  k_ctx<<<g2, 256, 0, stream>>>(ek, vb, ctxpart);

  k_mt<<<64, 256, 0, stream>>>(ctxpart, S, w_out, Mt);

  k_out<<<256, 512, 0, stream>>>(qs, Mt, gamma, out);
}

// Round 10
// 199.814 us; speedup vs baseline: 2.6656x; 1.0273x over previous
//
#include <hip/hip_runtime.h>
#include <hip/hip_bf16.h>
#include <stdint.h>
#include <stddef.h>

typedef __bf16 bf16_t;
typedef __bf16 bf16x8 __attribute__((ext_vector_type(8)));
typedef float floatx4 __attribute__((ext_vector_type(4)));

#define DIM 512
#define SEQ 4096
#define BATCH 8

static __device__ __forceinline__ floatx4 mfma_bf16(bf16x8 a, bf16x8 b, floatx4 c) {
  return __builtin_amdgcn_mfma_f32_16x16x32_bf16(a, b, c, 0, 0, 0);
}

typedef __attribute__((address_space(1))) const void* gas_ptr;
typedef __attribute__((address_space(3))) void* las_ptr;
static __device__ __forceinline__ void gll16(const void* g, void* l) {
  __builtin_amdgcn_global_load_lds((gas_ptr)g, (las_ptr)l, 16, 0, 0);
}

// ---------------- K0: fp32 -> bf16 converter (w_qkv and x) ----------------
__global__ __launch_bounds__(256) void k_cvt(const float* __restrict__ w, bf16_t* __restrict__ wb) {
  int i = (blockIdx.x * 256 + threadIdx.x) * 8;
  float4 a = *(const float4*)&w[i];
  float4 b = *(const float4*)&w[i + 4];
  bf16x8 o;
  o[0] = (bf16_t)a.x; o[1] = (bf16_t)a.y; o[2] = (bf16_t)a.z; o[3] = (bf16_t)a.w;
  o[4] = (bf16_t)b.x; o[5] = (bf16_t)b.y; o[6] = (bf16_t)b.z; o[7] = (bf16_t)b.w;
  *(bf16x8*)&wb[i] = o;
}

// ---------------- K1: qkv GEMM, 256x256 tile, 8 waves, BK=64, DOUBLE-BUFFERED ----------------
// 128B rows + u^(row&7): the only verified 0-conflict pattern (r5/r6; r8's 64B rows conflicted).
__global__ __launch_bounds__(512, 2) void k_qkv(const bf16_t* __restrict__ Xb,
                                                const bf16_t* __restrict__ Wb,
                                                bf16_t* __restrict__ qs,
                                                bf16_t* __restrict__ ek,
                                                bf16_t* __restrict__ vb,
                                                float* __restrict__ S) {
  __shared__ __align__(16) bf16_t As[2][256 * 64];  // 2 x 32 KB
  __shared__ __align__(16) bf16_t Bs[2][256 * 64];  // 2 x 32 KB
  const int tid = threadIdx.x;
  const int lane = tid & 63;
  const int w = tid >> 6;
  const int wr = w >> 2, wc = w & 3;   // wave tile 128 x 64
  const int l15 = lane & 15, l4 = lane >> 4;
  const int m0 = blockIdx.x * 256;
  const int n0 = blockIdx.y * 256;

  int sr[4], su[4];
#pragma unroll
  for (int i = 0; i < 4; ++i) {
    int s = tid + i * 512;
    sr[i] = s >> 3;
    su[i] = ((s & 7) ^ (sr[i] & 7)) << 3;
  }

  floatx4 acc[8][4];
#pragma unroll
  for (int i = 0; i < 8; ++i)
#pragma unroll
    for (int j = 0; j < 4; ++j) acc[i][j] = (floatx4){0.f, 0.f, 0.f, 0.f};

#pragma unroll
  for (int i = 0; i < 4; ++i) {
    int s = tid + i * 512;
    gll16(Xb + (size_t)(m0 + sr[i]) * DIM + su[i], &As[0][s * 8]);
    gll16(Wb + (size_t)(n0 + sr[i]) * DIM + su[i], &Bs[0][s * 8]);
  }
  __syncthreads();

  for (int t = 0; t < 8; ++t) {
    const int cur = t & 1;
    if (t < 7) {
      const int kt = (t + 1) * 64;
#pragma unroll
      for (int i = 0; i < 4; ++i) {
        int s = tid + i * 512;
        gll16(Xb + (size_t)(m0 + sr[i]) * DIM + kt + su[i], &As[cur ^ 1][s * 8]);
        gll16(Wb + (size_t)(n0 + sr[i]) * DIM + kt + su[i], &Bs[cur ^ 1][s * 8]);
      }
    }
#pragma unroll
    for (int kk = 0; kk < 2; ++kk) {
      bf16x8 af[8], bfr[4];
#pragma unroll
      for (int f = 0; f < 8; ++f) {
        int ar = wr * 128 + f * 16 + l15;
        int ua = (kk * 4 + l4) ^ (ar & 7);
        af[f] = *(const bf16x8*)(&As[cur][ar * 64 + ua * 8]);
      }
#pragma unroll
      for (int f = 0; f < 4; ++f) {
        int br = wc * 64 + f * 16 + l15;
        int ub = (kk * 4 + l4) ^ (br & 7);
        bfr[f] = *(const bf16x8*)(&Bs[cur][br * 64 + ub * 8]);
      }
#pragma unroll
      for (int i = 0; i < 8; ++i)
#pragma unroll
        for (int j = 0; j < 4; ++j)
          acc[i][j] = mfma_bf16(af[i], bfr[j], acc[i][j]);
    }
    __syncthreads();
  }

  const int colbase = n0 + wc * 64;
  if (n0 < 512) {
#pragma unroll
    for (int fm = 0; fm < 8; ++fm) {
#pragma unroll
      for (int r = 0; r < 4; ++r) {
        float v0 = acc[fm][0][r], v1 = acc[fm][1][r], v2 = acc[fm][2][r], v3 = acc[fm][3][r];
        float mx = fmaxf(fmaxf(v0, v1), fmaxf(v2, v3));
        mx = fmaxf(mx, __shfl_xor(mx, 1));
        mx = fmaxf(mx, __shfl_xor(mx, 2));
        mx = fmaxf(mx, __shfl_xor(mx, 4));
        mx = fmaxf(mx, __shfl_xor(mx, 8));
        float e0 = __expf(v0 - mx), e1 = __expf(v1 - mx), e2 = __expf(v2 - mx), e3 = __expf(v3 - mx);
        float s = e0 + e1 + e2 + e3;
        s += __shfl_xor(s, 1); s += __shfl_xor(s, 2); s += __shfl_xor(s, 4); s += __shfl_xor(s, 8);
        float inv = 0.125f / s;
        int m = m0 + wr * 128 + fm * 16 + l4 * 4 + r;
        bf16_t* rowp = qs + (size_t)m * DIM + colbase;
        rowp[l15]      = (bf16_t)(e0 * inv);
        rowp[16 + l15] = (bf16_t)(e1 * inv);
        rowp[32 + l15] = (bf16_t)(e2 * inv);
        rowp[48 + l15] = (bf16_t)(e3 * inv);
      }
    }
  } else if (n0 < 1024) {
    const int cb = colbase - 512;
    float c0 = 0.f, c1 = 0.f, c2 = 0.f, c3 = 0.f;
#pragma unroll
    for (int fm = 0; fm < 8; ++fm) {
#pragma unroll
      for (int r = 0; r < 4; ++r) {
        int m = m0 + wr * 128 + fm * 16 + l4 * 4 + r;
        bf16_t* rowp = ek + (size_t)m * DIM + cb;
        float e0 = __expf(acc[fm][0][r]);
        float e1 = __expf(acc[fm][1][r]);
        float e2 = __expf(acc[fm][2][r]);
        float e3 = __expf(acc[fm][3][r]);
        rowp[l15]      = (bf16_t)e0;
        rowp[16 + l15] = (bf16_t)e1;
        rowp[32 + l15] = (bf16_t)e2;
        rowp[48 + l15] = (bf16_t)e3;
        c0 += e0; c1 += e1; c2 += e2; c3 += e3;
      }
    }
    c0 += __shfl_xor(c0, 16); c0 += __shfl_xor(c0, 32);
    c1 += __shfl_xor(c1, 16); c1 += __shfl_xor(c1, 32);
    c2 += __shfl_xor(c2, 16); c2 += __shfl_xor(c2, 32);
    c3 += __shfl_xor(c3, 16); c3 += __shfl_xor(c3, 32);
    if (lane < 16) {
      int b = m0 >> 12;
      atomicAdd(&S[b * 512 + cb + lane],      c0);
      atomicAdd(&S[b * 512 + cb + 16 + lane], c1);
      atomicAdd(&S[b * 512 + cb + 32 + lane], c2);
      atomicAdd(&S[b * 512 + cb + 48 + lane], c3);
    }
  } else {
    const int cb = colbase - 1024;
#pragma unroll
    for (int fm = 0; fm < 8; ++fm) {
#pragma unroll
      for (int r = 0; r < 4; ++r) {
        int m = m0 + wr * 128 + fm * 16 + l4 * 4 + r;
        bf16_t* rowp = vb + (size_t)m * DIM + cb;
        rowp[l15]      = (bf16_t)acc[fm][0][r];
        rowp[16 + l15] = (bf16_t)acc[fm][1][r];
        rowp[32 + l15] = (bf16_t)acc[fm][2][r];
        rowp[48 + l15] = (bf16_t)acc[fm][3][r];
      }
    }
  }
}

// ---------------- K2: ctxpart = ek_chunk^T @ v_chunk — COALESCED staging + XOR-swizzled transpose ----------------
// Load: 8 lanes cover one row's 64 cols (128B contiguous) -> full coalescing (was 16B/lane @1KB stride = 4x overfetch).
// LDS: element (c, n) stored at col n ^ ((c>>3)<<3); write banks exactly 2-way (free), b128 reads ~2-way.
#define TP 136
__global__ __launch_bounds__(256) void k_ctx(const bf16_t* __restrict__ ek,
                                             const bf16_t* __restrict__ vb,
                                             float* __restrict__ ctxpart) {
  __shared__ __align__(16) bf16_t ekT[64 * TP];
  __shared__ __align__(16) bf16_t vT[64 * TP];
  __shared__ float red[4096];
  const int tid = threadIdx.x;
  const int lane = tid & 63, wid = tid >> 6;
  const int l15 = lane & 15, l4 = lane >> 4;
  const int bh = blockIdx.x, chunk = blockIdx.y;
  const int b = bh >> 3, h = bh & 7;
  const int base = b * SEQ + chunk * 512;

  floatx4 acc[4][4];
#pragma unroll
  for (int i = 0; i < 4; ++i)
#pragma unroll
    for (int j = 0; j < 4; ++j) acc[i][j] = (floatx4){0.f, 0.f, 0.f, 0.f};

  for (int nt = 0; nt < 4; ++nt) {
    const int n0 = base + nt * 128;
    if (nt) __syncthreads();   // previous iteration's reads done before overwrite
#pragma unroll
    for (int i = 0; i < 4; ++i) {
      int q = tid + i * 256;          // 1024 slots: row n = q>>3 (0..127), unit u = q&7
      int n = q >> 3;
      int u = q & 7;
      bf16x8 vk = *(const bf16x8*)&ek[(size_t)(n0 + n) * DIM + h * 64 + u * 8];
      bf16x8 vv = *(const bf16x8*)&vb[(size_t)(n0 + n) * DIM + h * 64 + u * 8];
      int ncol = n ^ (u << 3);
#pragma unroll
      for (int j = 0; j < 8; ++j) {
        int c = u * 8 + j;
        ekT[c * TP + ncol] = vk[j];
        vT [c * TP + ncol] = vv[j];
      }
    }
    __syncthreads();
    const int nb = wid * 32;   // each wave takes a disjoint K=32 slice
    bf16x8 af[4], bfr[4];
#pragma unroll
    for (int f = 0; f < 4; ++f) {
      int c = f * 16 + l15;
      int colstart = (nb + l4 * 8) ^ (((c >> 3) & 7) << 3);
      af[f]  = *(const bf16x8*)&ekT[c * TP + colstart];
      bfr[f] = *(const bf16x8*)&vT [c * TP + colstart];
    }
#pragma unroll
    for (int i = 0; i < 4; ++i)
#pragma unroll
      for (int j = 0; j < 4; ++j)
        acc[i][j] = mfma_bf16(af[i], bfr[j], acc[i][j]);
  }

  __syncthreads();
  for (int w = 0; w < 4; ++w) {
    if (wid == w) {
#pragma unroll
      for (int fm = 0; fm < 4; ++fm)
#pragma unroll
        for (int fn = 0; fn < 4; ++fn)
#pragma unroll
          for (int r = 0; r < 4; ++r) {
            int d = fm * 16 + l4 * 4 + r;
            int e = fn * 16 + l15;
            if (w == 0) red[d * 64 + e] = acc[fm][fn][r];
            else        red[d * 64 + e] += acc[fm][fn][r];
          }
    }
    __syncthreads();
  }
  float* dst = ctxpart + ((size_t)bh * 8 + chunk) * 4096;
#pragma unroll
  for (int i = 0; i < 4; ++i) {
    int q = tid + i * 256;
    *(float4*)&dst[q * 4] = *(const float4*)&red[q * 4];
  }
}

// ---------------- K3: reduce partials, /S, then Mt[b][dcol][h*64+d] ----------------
__global__ __launch_bounds__(256) void k_mt(const float* __restrict__ ctxpart,
                                            const float* __restrict__ S,
                                            const float* __restrict__ w_out,
                                            bf16_t* __restrict__ Mt) {
  __shared__ float cs[4096];
  const int tid = threadIdx.x;
  const int bh = blockIdx.x;
  const int b = bh >> 3, h = bh & 7;
#pragma unroll
  for (int i = 0; i < 16; ++i) {
    int idx = tid + i * 256;
    float s = 0.f;
#pragma unroll
    for (int p = 0; p < 8; ++p) s += ctxpart[((size_t)bh * 8 + p) * 4096 + idx];
    cs[idx] = s / S[b * 512 + h * 64 + (idx >> 6)];
  }
  __syncthreads();
  for (int half = 0; half < 2; ++half) {
    const int dcol = half * 256 + tid;
    float a[64];
#pragma unroll
    for (int d = 0; d < 64; ++d) a[d] = 0.f;
    for (int e = 0; e < 64; ++e) {
      float we = w_out[(size_t)dcol * 512 + h * 64 + e];
#pragma unroll
      for (int d = 0; d < 64; ++d) a[d] += cs[d * 64 + e] * we;
    }
    bf16_t* dst = Mt + ((size_t)b * 512 + dcol) * 512 + h * 64;
#pragma unroll
    for (int g = 0; g < 8; ++g) {
      bf16x8 o;
#pragma unroll
      for (int j = 0; j < 8; ++j) o[j] = (bf16_t)a[g * 8 + j];
      *(bf16x8*)&dst[g * 8] = o;
    }
  }
}

// ---------------- K4: out = LN(qs[b] @ Mt[b]) fused. 512 thr (512,2), tile 128x512, wave 64x128, BK=64 ----------------
__global__ __launch_bounds__(512, 2) void k_out(const bf16_t* __restrict__ qs,
                                                const bf16_t* __restrict__ Mt,
                                                const float* __restrict__ gamma,
                                                float* __restrict__ out) {
  __shared__ __align__(16) bf16_t As[128 * 64];   // 16 KB
  __shared__ __align__(16) bf16_t Bs[512 * 64];   // 64 KB
  __shared__ float redS[128 * 4];
  __shared__ float redQ[128 * 4];
  const int tid = threadIdx.x;
  const int lane = tid & 63;
  const int w = tid >> 6;
  const int wr = w >> 2, wc = w & 3;   // wave tile: 64 rows x 128 cols
  const int l15 = lane & 15, l4 = lane >> 4;
  const int m0 = blockIdx.x * 128;
  const bf16_t* Bp = Mt + (size_t)(blockIdx.x >> 5) * 512 * 512;

  floatx4 acc[4][8];
#pragma unroll
  for (int i = 0; i < 4; ++i)
#pragma unroll
    for (int j = 0; j < 8; ++j) acc[i][j] = (floatx4){0.f, 0.f, 0.f, 0.f};

  for (int kt = 0; kt < 512; kt += 64) {
#pragma unroll
    for (int i = 0; i < 2; ++i) {
      int s = tid + i * 512;
      int r = s >> 3;
      int u = ((s & 7) ^ (r & 7)) << 3;
      gll16(qs + (size_t)(m0 + r) * 512 + kt + u, &As[s * 8]);
    }
#pragma unroll
    for (int i = 0; i < 8; ++i) {
      int s = tid + i * 512;
      int r = s >> 3;
      int u = ((s & 7) ^ (r & 7)) << 3;
      gll16(Bp + (size_t)r * 512 + kt + u, &Bs[s * 8]);
    }
    __syncthreads();
#pragma unroll
    for (int kk = 0; kk < 2; ++kk) {
      bf16x8 af[4], bfr[8];
#pragma unroll
      for (int f = 0; f < 4; ++f) {
        int ar = wr * 64 + f * 16 + l15;
        int ua = (kk * 4 + l4) ^ (ar & 7);
        af[f] = *(const bf16x8*)(&As[ar * 64 + ua * 8]);
      }
#pragma unroll
      for (int f = 0; f < 8; ++f) {
        int br = wc * 128 + f * 16 + l15;
        int ub = (kk * 4 + l4) ^ (br & 7);
        bfr[f] = *(const bf16x8*)(&Bs[br * 64 + ub * 8]);
      }
#pragma unroll
      for (int i = 0; i < 4; ++i)
#pragma unroll
        for (int j = 0; j < 8; ++j)
          acc[i][j] = mfma_bf16(af[i], bfr[j], acc[i][j]);
    }
    __syncthreads();
  }

#pragma unroll
  for (int fm = 0; fm < 4; ++fm) {
#pragma unroll
    for (int r = 0; r < 4; ++r) {
      float s = 0.f, q = 0.f;
#pragma unroll
      for (int fn = 0; fn < 8; ++fn) {
        float v = acc[fm][fn][r];
        s += v; q += v * v;
      }
      s += __shfl_xor(s, 1); q += __shfl_xor(q, 1);
      s += __shfl_xor(s, 2); q += __shfl_xor(q, 2);
      s += __shfl_xor(s, 4); q += __shfl_xor(q, 4);
      s += __shfl_xor(s, 8); q += __shfl_xor(q, 8);
      if (l15 == 0) {
        int rl = wr * 64 + fm * 16 + l4 * 4 + r;
        redS[rl * 4 + wc] = s;
        redQ[rl * 4 + wc] = q;
      }
    }
  }
  __syncthreads();
  float gm[8];
#pragma unroll
  for (int fn = 0; fn < 8; ++fn) gm[fn] = gamma[wc * 128 + fn * 16 + l15];
#pragma unroll
  for (int fm = 0; fm < 4; ++fm) {
#pragma unroll
    for (int r = 0; r < 4; ++r) {
      int rl = wr * 64 + fm * 16 + l4 * 4 + r;
      float4 sv = *(const float4*)&redS[rl * 4];
      float4 qv = *(const float4*)&redQ[rl * 4];
      float Sr = sv.x + sv.y + sv.z + sv.w;
      float Qr = qv.x + qv.y + qv.z + qv.w;
      float mean = Sr * (1.f / 512.f);
      float var = Qr * (1.f / 512.f) - mean * mean;
      float rstd = rsqrtf(var + 1e-5f);
      float* rowp = out + (size_t)(m0 + rl) * 512 + wc * 128 + l15;
#pragma unroll
      for (int fn = 0; fn < 8; ++fn)
        rowp[fn * 16] = (acc[fm][fn][r] - mean) * rstd * gm[fn];
    }
  }
}

extern "C" void kernel_launch(void* const* d_in, const int* in_sizes, int n_in,
                              void* d_out, int out_size, void* d_ws, size_t ws_size,
                              hipStream_t stream) {
  const float* x     = (const float*)d_in[0];
  const float* w_qkv = (const float*)d_in[1];
  const float* w_out = (const float*)d_in[2];
  const float* gamma = (const float*)d_in[3];
  float* out = (float*)d_out;
  char* ws = (char*)d_ws;

  bf16_t* qs      = (bf16_t*)(ws);                       // 33,554,432
  bf16_t* ek      = (bf16_t*)(ws + 33554432);            // 33,554,432
  bf16_t* vb      = (bf16_t*)(ws + 67108864);            // 33,554,432
  bf16_t* wqkvb   = (bf16_t*)(ws + 100663296);           //  1,572,864
  float*  S       = (float*)(ws + 102236160);            //     16,384
  bf16_t* Xb      = (bf16_t*)(ws + 102252544);           // 33,554,432 (dead after k_qkv)
  float*  ctxpart = (float*)(ws + 103301120);            // alias Xb tail (written post-k_qkv)
  bf16_t* Mt      = (bf16_t*)(ws + 111689728);           // alias Xb tail

  hipMemsetAsync(S, 0, BATCH * 512 * sizeof(float), stream);

  k_cvt<<<384, 256, 0, stream>>>(w_qkv, wqkvb);
  k_cvt<<<8192, 256, 0, stream>>>(x, Xb);

  dim3 g1(128, 6);
  k_qkv<<<g1, 512, 0, stream>>>(Xb, wqkvb, qs, ek, vb, S);

  dim3 g2(64, 8);
  k_ctx<<<g2, 256, 0, stream>>>(ek, vb, ctxpart);

  k_mt<<<64, 256, 0, stream>>>(ctxpart, S, w_out, Mt);

  k_out<<<256, 512, 0, stream>>>(qs, Mt, gamma, out);
}

// Round 11
// 196.823 us; speedup vs baseline: 2.7061x; 1.0152x over previous
//
#include <hip/hip_runtime.h>
#include <hip/hip_bf16.h>
#include <stdint.h>
#include <stddef.h>

typedef __bf16 bf16_t;
typedef __bf16 bf16x8 __attribute__((ext_vector_type(8)));
typedef float floatx4 __attribute__((ext_vector_type(4)));

#define DIM 512
#define SEQ 4096
#define BATCH 8

static __device__ __forceinline__ floatx4 mfma_bf16(bf16x8 a, bf16x8 b, floatx4 c) {
  return __builtin_amdgcn_mfma_f32_16x16x32_bf16(a, b, c, 0, 0, 0);
}

typedef __attribute__((address_space(1))) const void* gas_ptr;
typedef __attribute__((address_space(3))) void* las_ptr;
static __device__ __forceinline__ void gll16(const void* g, void* l) {
  __builtin_amdgcn_global_load_lds((gas_ptr)g, (las_ptr)l, 16, 0, 0);
}

// ---------------- K0: fp32 -> bf16 converter (w_qkv and x) ----------------
__global__ __launch_bounds__(256) void k_cvt(const float* __restrict__ w, bf16_t* __restrict__ wb) {
  int i = (blockIdx.x * 256 + threadIdx.x) * 8;
  float4 a = *(const float4*)&w[i];
  float4 b = *(const float4*)&w[i + 4];
  bf16x8 o;
  o[0] = (bf16_t)a.x; o[1] = (bf16_t)a.y; o[2] = (bf16_t)a.z; o[3] = (bf16_t)a.w;
  o[4] = (bf16_t)b.x; o[5] = (bf16_t)b.y; o[6] = (bf16_t)b.z; o[7] = (bf16_t)b.w;
  *(bf16x8*)&wb[i] = o;
}

// ---------------- K1: qkv GEMM, 256x256 tile, 8 waves, BK=64, dbuf + COUNTED vmcnt ----------------
// T4 recipe: issue prefetch -> s_waitcnt vmcnt(8) (new 8 stay in flight) -> raw barrier -> MFMA -> raw barrier.
// __syncthreads would drain vmcnt(0) and kill the overlap (r9 null result).
__global__ __launch_bounds__(512, 2) void k_qkv(const bf16_t* __restrict__ Xb,
                                                const bf16_t* __restrict__ Wb,
                                                bf16_t* __restrict__ qs,
                                                bf16_t* __restrict__ ek,
                                                bf16_t* __restrict__ vb,
                                                float* __restrict__ S) {
  __shared__ __align__(16) bf16_t As[2][256 * 64];  // 2 x 32 KB
  __shared__ __align__(16) bf16_t Bs[2][256 * 64];  // 2 x 32 KB
  const int tid = threadIdx.x;
  const int lane = tid & 63;
  const int w = tid >> 6;
  const int wr = w >> 2, wc = w & 3;   // wave tile 128 x 64
  const int l15 = lane & 15, l4 = lane >> 4;
  const int m0 = blockIdx.x * 256;
  const int n0 = blockIdx.y * 256;

  int sr[4], su[4];
#pragma unroll
  for (int i = 0; i < 4; ++i) {
    int s = tid + i * 512;
    sr[i] = s >> 3;
    su[i] = ((s & 7) ^ (sr[i] & 7)) << 3;
  }

  floatx4 acc[8][4];
#pragma unroll
  for (int i = 0; i < 8; ++i)
#pragma unroll
    for (int j = 0; j < 4; ++j) acc[i][j] = (floatx4){0.f, 0.f, 0.f, 0.f};

  // prologue: stage tile 0 into buf 0 (8 gll/thread)
#pragma unroll
  for (int i = 0; i < 4; ++i) {
    int s = tid + i * 512;
    gll16(Xb + (size_t)(m0 + sr[i]) * DIM + su[i], &As[0][s * 8]);
    gll16(Wb + (size_t)(n0 + sr[i]) * DIM + su[i], &Bs[0][s * 8]);
  }

  for (int t = 0; t < 8; ++t) {
    const int cur = t & 1;
    if (t < 7) {
      const int kt = (t + 1) * 64;
#pragma unroll
      for (int i = 0; i < 4; ++i) {
        int s = tid + i * 512;
        gll16(Xb + (size_t)(m0 + sr[i]) * DIM + kt + su[i], &As[cur ^ 1][s * 8]);
        gll16(Wb + (size_t)(n0 + sr[i]) * DIM + kt + su[i], &Bs[cur ^ 1][s * 8]);
      }
      asm volatile("s_waitcnt vmcnt(8)" ::: "memory");  // tile t landed; t+1's 8 stay in flight
    } else {
      asm volatile("s_waitcnt vmcnt(0)" ::: "memory");
    }
    __builtin_amdgcn_s_barrier();            // tile t visible to all waves
    __builtin_amdgcn_sched_barrier(0);
    __builtin_amdgcn_s_setprio(1);
#pragma unroll
    for (int kk = 0; kk < 2; ++kk) {
      bf16x8 af[8], bfr[4];
#pragma unroll
      for (int f = 0; f < 8; ++f) {
        int ar = wr * 128 + f * 16 + l15;
        int ua = (kk * 4 + l4) ^ (ar & 7);
        af[f] = *(const bf16x8*)(&As[cur][ar * 64 + ua * 8]);
      }
#pragma unroll
      for (int f = 0; f < 4; ++f) {
        int br = wc * 64 + f * 16 + l15;
        int ub = (kk * 4 + l4) ^ (br & 7);
        bfr[f] = *(const bf16x8*)(&Bs[cur][br * 64 + ub * 8]);
      }
#pragma unroll
      for (int i = 0; i < 8; ++i)
#pragma unroll
        for (int j = 0; j < 4; ++j)
          acc[i][j] = mfma_bf16(af[i], bfr[j], acc[i][j]);
    }
    __builtin_amdgcn_s_setprio(0);
    __builtin_amdgcn_sched_barrier(0);
    __builtin_amdgcn_s_barrier();            // all waves done reading buf[cur] before next overwrite
  }

  const int colbase = n0 + wc * 64;
  if (n0 < 512) {
#pragma unroll
    for (int fm = 0; fm < 8; ++fm) {
#pragma unroll
      for (int r = 0; r < 4; ++r) {
        float v0 = acc[fm][0][r], v1 = acc[fm][1][r], v2 = acc[fm][2][r], v3 = acc[fm][3][r];
        float mx = fmaxf(fmaxf(v0, v1), fmaxf(v2, v3));
        mx = fmaxf(mx, __shfl_xor(mx, 1));
        mx = fmaxf(mx, __shfl_xor(mx, 2));
        mx = fmaxf(mx, __shfl_xor(mx, 4));
        mx = fmaxf(mx, __shfl_xor(mx, 8));
        float e0 = __expf(v0 - mx), e1 = __expf(v1 - mx), e2 = __expf(v2 - mx), e3 = __expf(v3 - mx);
        float s = e0 + e1 + e2 + e3;
        s += __shfl_xor(s, 1); s += __shfl_xor(s, 2); s += __shfl_xor(s, 4); s += __shfl_xor(s, 8);
        float inv = 0.125f / s;
        int m = m0 + wr * 128 + fm * 16 + l4 * 4 + r;
        bf16_t* rowp = qs + (size_t)m * DIM + colbase;
        rowp[l15]      = (bf16_t)(e0 * inv);
        rowp[16 + l15] = (bf16_t)(e1 * inv);
        rowp[32 + l15] = (bf16_t)(e2 * inv);
        rowp[48 + l15] = (bf16_t)(e3 * inv);
      }
    }
  } else if (n0 < 1024) {
    const int cb = colbase - 512;
    float c0 = 0.f, c1 = 0.f, c2 = 0.f, c3 = 0.f;
#pragma unroll
    for (int fm = 0; fm < 8; ++fm) {
#pragma unroll
      for (int r = 0; r < 4; ++r) {
        int m = m0 + wr * 128 + fm * 16 + l4 * 4 + r;
        bf16_t* rowp = ek + (size_t)m * DIM + cb;
        float e0 = __expf(acc[fm][0][r]);
        float e1 = __expf(acc[fm][1][r]);
        float e2 = __expf(acc[fm][2][r]);
        float e3 = __expf(acc[fm][3][r]);
        rowp[l15]      = (bf16_t)e0;
        rowp[16 + l15] = (bf16_t)e1;
        rowp[32 + l15] = (bf16_t)e2;
        rowp[48 + l15] = (bf16_t)e3;
        c0 += e0; c1 += e1; c2 += e2; c3 += e3;
      }
    }
    c0 += __shfl_xor(c0, 16); c0 += __shfl_xor(c0, 32);
    c1 += __shfl_xor(c1, 16); c1 += __shfl_xor(c1, 32);
    c2 += __shfl_xor(c2, 16); c2 += __shfl_xor(c2, 32);
    c3 += __shfl_xor(c3, 16); c3 += __shfl_xor(c3, 32);
    if (lane < 16) {
      int b = m0 >> 12;
      atomicAdd(&S[b * 512 + cb + lane],      c0);
      atomicAdd(&S[b * 512 + cb + 16 + lane], c1);
      atomicAdd(&S[b * 512 + cb + 32 + lane], c2);
      atomicAdd(&S[b * 512 + cb + 48 + lane], c3);
    }
  } else {
    const int cb = colbase - 1024;
#pragma unroll
    for (int fm = 0; fm < 8; ++fm) {
#pragma unroll
      for (int r = 0; r < 4; ++r) {
        int m = m0 + wr * 128 + fm * 16 + l4 * 4 + r;
        bf16_t* rowp = vb + (size_t)m * DIM + cb;
        rowp[l15]      = (bf16_t)acc[fm][0][r];
        rowp[16 + l15] = (bf16_t)acc[fm][1][r];
        rowp[32 + l15] = (bf16_t)acc[fm][2][r];
        rowp[48 + l15] = (bf16_t)acc[fm][3][r];
      }
    }
  }
}

// ---------------- K2: ctxpart = ek_chunk^T @ v_chunk — coalesced staging + XOR-swizzled transpose ----------------
#define TP 136
__global__ __launch_bounds__(256) void k_ctx(const bf16_t* __restrict__ ek,
                                             const bf16_t* __restrict__ vb,
                                             float* __restrict__ ctxpart) {
  __shared__ __align__(16) bf16_t ekT[64 * TP];
  __shared__ __align__(16) bf16_t vT[64 * TP];
  __shared__ float red[4096];
  const int tid = threadIdx.x;
  const int lane = tid & 63, wid = tid >> 6;
  const int l15 = lane & 15, l4 = lane >> 4;
  const int bh = blockIdx.x, chunk = blockIdx.y;
  const int b = bh >> 3, h = bh & 7;
  const int base = b * SEQ + chunk * 512;

  floatx4 acc[4][4];
#pragma unroll
  for (int i = 0; i < 4; ++i)
#pragma unroll
    for (int j = 0; j < 4; ++j) acc[i][j] = (floatx4){0.f, 0.f, 0.f, 0.f};

  for (int nt = 0; nt < 4; ++nt) {
    const int n0 = base + nt * 128;
    if (nt) __syncthreads();
#pragma unroll
    for (int i = 0; i < 4; ++i) {
      int q = tid + i * 256;
      int n = q >> 3;
      int u = q & 7;
      bf16x8 vk = *(const bf16x8*)&ek[(size_t)(n0 + n) * DIM + h * 64 + u * 8];
      bf16x8 vv = *(const bf16x8*)&vb[(size_t)(n0 + n) * DIM + h * 64 + u * 8];
      int ncol = n ^ (u << 3);
#pragma unroll
      for (int j = 0; j < 8; ++j) {
        int c = u * 8 + j;
        ekT[c * TP + ncol] = vk[j];
        vT [c * TP + ncol] = vv[j];
      }
    }
    __syncthreads();
    const int nb = wid * 32;
    bf16x8 af[4], bfr[4];
#pragma unroll
    for (int f = 0; f < 4; ++f) {
      int c = f * 16 + l15;
      int colstart = (nb + l4 * 8) ^ (((c >> 3) & 7) << 3);
      af[f]  = *(const bf16x8*)&ekT[c * TP + colstart];
      bfr[f] = *(const bf16x8*)&vT [c * TP + colstart];
    }
#pragma unroll
    for (int i = 0; i < 4; ++i)
#pragma unroll
      for (int j = 0; j < 4; ++j)
        acc[i][j] = mfma_bf16(af[i], bfr[j], acc[i][j]);
  }

  __syncthreads();
  for (int w = 0; w < 4; ++w) {
    if (wid == w) {
#pragma unroll
      for (int fm = 0; fm < 4; ++fm)
#pragma unroll
        for (int fn = 0; fn < 4; ++fn)
#pragma unroll
          for (int r = 0; r < 4; ++r) {
            int d = fm * 16 + l4 * 4 + r;
            int e = fn * 16 + l15;
            if (w == 0) red[d * 64 + e] = acc[fm][fn][r];
            else        red[d * 64 + e] += acc[fm][fn][r];
          }
    }
    __syncthreads();
  }
  float* dst = ctxpart + ((size_t)bh * 8 + chunk) * 4096;
#pragma unroll
  for (int i = 0; i < 4; ++i) {
    int q = tid + i * 256;
    *(float4*)&dst[q * 4] = *(const float4*)&red[q * 4];
  }
}

// ---------------- K3: reduce partials, /S, then Mt[b][dcol][h*64+d] ----------------
__global__ __launch_bounds__(256) void k_mt(const float* __restrict__ ctxpart,
                                            const float* __restrict__ S,
                                            const float* __restrict__ w_out,
                                            bf16_t* __restrict__ Mt) {
  __shared__ float cs[4096];
  const int tid = threadIdx.x;
  const int bh = blockIdx.x;
  const int b = bh >> 3, h = bh & 7;
#pragma unroll
  for (int i = 0; i < 16; ++i) {
    int idx = tid + i * 256;
    float s = 0.f;
#pragma unroll
    for (int p = 0; p < 8; ++p) s += ctxpart[((size_t)bh * 8 + p) * 4096 + idx];
    cs[idx] = s / S[b * 512 + h * 64 + (idx >> 6)];
  }
  __syncthreads();
  for (int half = 0; half < 2; ++half) {
    const int dcol = half * 256 + tid;
    float a[64];
#pragma unroll
    for (int d = 0; d < 64; ++d) a[d] = 0.f;
    for (int e = 0; e < 64; ++e) {
      float we = w_out[(size_t)dcol * 512 + h * 64 + e];
#pragma unroll
      for (int d = 0; d < 64; ++d) a[d] += cs[d * 64 + e] * we;
    }
    bf16_t* dst = Mt + ((size_t)b * 512 + dcol) * 512 + h * 64;
#pragma unroll
    for (int g = 0; g < 8; ++g) {
      bf16x8 o;
#pragma unroll
      for (int j = 0; j < 8; ++j) o[j] = (bf16_t)a[g * 8 + j];
      *(bf16x8*)&dst[g * 8] = o;
    }
  }
}

// ---------------- K4: out = LN(qs[b] @ Mt[b]) fused. 512 thr (512,2), tile 128x512, wave 64x128, BK=64 ----------------
__global__ __launch_bounds__(512, 2) void k_out(const bf16_t* __restrict__ qs,
                                                const bf16_t* __restrict__ Mt,
                                                const float* __restrict__ gamma,
                                                float* __restrict__ out) {
  __shared__ __align__(16) bf16_t As[128 * 64];   // 16 KB
  __shared__ __align__(16) bf16_t Bs[512 * 64];   // 64 KB
  __shared__ float redS[128 * 4];
  __shared__ float redQ[128 * 4];
  const int tid = threadIdx.x;
  const int lane = tid & 63;
  const int w = tid >> 6;
  const int wr = w >> 2, wc = w & 3;
  const int l15 = lane & 15, l4 = lane >> 4;
  const int m0 = blockIdx.x * 128;
  const bf16_t* Bp = Mt + (size_t)(blockIdx.x >> 5) * 512 * 512;

  floatx4 acc[4][8];
#pragma unroll
  for (int i = 0; i < 4; ++i)
#pragma unroll
    for (int j = 0; j < 8; ++j) acc[i][j] = (floatx4){0.f, 0.f, 0.f, 0.f};

  for (int kt = 0; kt < 512; kt += 64) {
#pragma unroll
    for (int i = 0; i < 2; ++i) {
      int s = tid + i * 512;
      int r = s >> 3;
      int u = ((s & 7) ^ (r & 7)) << 3;
      gll16(qs + (size_t)(m0 + r) * 512 + kt + u, &As[s * 8]);
    }
#pragma unroll
    for (int i = 0; i < 8; ++i) {
      int s = tid + i * 512;
      int r = s >> 3;
      int u = ((s & 7) ^ (r & 7)) << 3;
      gll16(Bp + (size_t)r * 512 + kt + u, &Bs[s * 8]);
    }
    __syncthreads();
#pragma unroll
    for (int kk = 0; kk < 2; ++kk) {
      bf16x8 af[4], bfr[8];
#pragma unroll
      for (int f = 0; f < 4; ++f) {
        int ar = wr * 64 + f * 16 + l15;
        int ua = (kk * 4 + l4) ^ (ar & 7);
        af[f] = *(const bf16x8*)(&As[ar * 64 + ua * 8]);
      }
#pragma unroll
      for (int f = 0; f < 8; ++f) {
        int br = wc * 128 + f * 16 + l15;
        int ub = (kk * 4 + l4) ^ (br & 7);
        bfr[f] = *(const bf16x8*)(&Bs[br * 64 + ub * 8]);
      }
#pragma unroll
      for (int i = 0; i < 4; ++i)
#pragma unroll
        for (int j = 0; j < 8; ++j)
          acc[i][j] = mfma_bf16(af[i], bfr[j], acc[i][j]);
    }
    __syncthreads();
  }

#pragma unroll
  for (int fm = 0; fm < 4; ++fm) {
#pragma unroll
    for (int r = 0; r < 4; ++r) {
      float s = 0.f, q = 0.f;
#pragma unroll
      for (int fn = 0; fn < 8; ++fn) {
        float v = acc[fm][fn][r];
        s += v; q += v * v;
      }
      s += __shfl_xor(s, 1); q += __shfl_xor(q, 1);
      s += __shfl_xor(s, 2); q += __shfl_xor(q, 2);
      s += __shfl_xor(s, 4); q += __shfl_xor(q, 4);
      s += __shfl_xor(s, 8); q += __shfl_xor(q, 8);
      if (l15 == 0) {
        int rl = wr * 64 + fm * 16 + l4 * 4 + r;
        redS[rl * 4 + wc] = s;
        redQ[rl * 4 + wc] = q;
      }
    }
  }
  __syncthreads();
  float gm[8];
#pragma unroll
  for (int fn = 0; fn < 8; ++fn) gm[fn] = gamma[wc * 128 + fn * 16 + l15];
#pragma unroll
  for (int fm = 0; fm < 4; ++fm) {
#pragma unroll
    for (int r = 0; r < 4; ++r) {
      int rl = wr * 64 + fm * 16 + l4 * 4 + r;
      float4 sv = *(const float4*)&redS[rl * 4];
      float4 qv = *(const float4*)&redQ[rl * 4];
      float Sr = sv.x + sv.y + sv.z + sv.w;
      float Qr = qv.x + qv.y + qv.z + qv.w;
      float mean = Sr * (1.f / 512.f);
      float var = Qr * (1.f / 512.f) - mean * mean;
      float rstd = rsqrtf(var + 1e-5f);
      float* rowp = out + (size_t)(m0 + rl) * 512 + wc * 128 + l15;
#pragma unroll
      for (int fn = 0; fn < 8; ++fn)
        rowp[fn * 16] = (acc[fm][fn][r] - mean) * rstd * gm[fn];
    }
  }
}

extern "C" void kernel_launch(void* const* d_in, const int* in_sizes, int n_in,
                              void* d_out, int out_size, void* d_ws, size_t ws_size,
                              hipStream_t stream) {
  const float* x     = (const float*)d_in[0];
  const float* w_qkv = (const float*)d_in[1];
  const float* w_out = (const float*)d_in[2];
  const float* gamma = (const float*)d_in[3];
  float* out = (float*)d_out;
  char* ws = (char*)d_ws;

  bf16_t* qs      = (bf16_t*)(ws);                       // 33,554,432
  bf16_t* ek      = (bf16_t*)(ws + 33554432);            // 33,554,432
  bf16_t* vb      = (bf16_t*)(ws + 67108864);            // 33,554,432
  bf16_t* wqkvb   = (bf16_t*)(ws + 100663296);           //  1,572,864
  float*  S       = (float*)(ws + 102236160);            //     16,384
  bf16_t* Xb      = (bf16_t*)(ws + 102252544);           // 33,554,432 (dead after k_qkv)
  float*  ctxpart = (float*)(ws + 103301120);            // alias Xb tail
  bf16_t* Mt      = (bf16_t*)(ws + 111689728);           // alias Xb tail

  hipMemsetAsync(S, 0, BATCH * 512 * sizeof(float), stream);

  k_cvt<<<384, 256, 0, stream>>>(w_qkv, wqkvb);
  k_cvt<<<8192, 256, 0, stream>>>(x, Xb);

  dim3 g1(128, 6);
  k_qkv<<<g1, 512, 0, stream>>>(Xb, wqkvb, qs, ek, vb, S);

  dim3 g2(64, 8);
  k_ctx<<<g2, 256, 0, stream>>>(ek, vb, ctxpart);

  k_mt<<<64, 256, 0, stream>>>(ctxpart, S, w_out, Mt);

  k_out<<<256, 512, 0, stream>>>(qs, Mt, gamma, out);
}